// Round 1
// baseline (1536.274 us; speedup 1.0000x reference)
//
#include <hip/hip_runtime.h>
#include <math.h>

// ---------------------------------------------------------------------------
// SophisticatedBioInspiredModel: fused bf16-MFMA implementation for gfx950.
//
// Key insight: the spiking top-k attention is data-independent. tok holds 100
// DISTINCT indices (<2048); each is incremented once from a decayed-zero state
// so v[ti]=1.0 < theta=1.2 -> no spikes -> counts==0 -> top_k picks indices
// 0..19 -> gains[0..19]=2. "attended = context with cols 0..19 doubled".
// ---------------------------------------------------------------------------

typedef __attribute__((ext_vector_type(8))) short bfrag8;   // 8 bf16 (4 VGPR)
typedef __attribute__((ext_vector_type(4))) float facc4;    // 4 f32 acc

#define BM 128
#define BN 128
#define BK 32
#define LDT 40   // padded LDS row length (elems); 80B row stride, 16B aligned

__device__ __forceinline__ unsigned short f2bf(float f) {
  union { float f; unsigned u; } c; c.f = f;
  unsigned u = c.u;
  return (unsigned short)((u + 0x7fffu + ((u >> 16) & 1u)) >> 16);
}
__device__ __forceinline__ float bf2f(unsigned short h) {
  union { unsigned u; float f; } c; c.u = ((unsigned)h) << 16;
  return c.f;
}

enum { EP_PROJ = 0, EP_EXPERT = 1, EP_CTX = 2, EP_RELU = 3, EP_OUT = 4 };

// Generic 128x128 bf16-MFMA GEMM, C = A(MxK) * B(KxN), fused epilogues.
// A: bf16 (ushort) if ABF else f32. B: f32, converted to bf16 at staging.
// B col-block base = Bp + bx*bstride; element (k, c_local) at [k*ldb+c_local].
template<bool ABF, int EP>
__global__ __launch_bounds__(256)
void gemm_k(const void* __restrict__ Ap, const float* __restrict__ Bp,
            const float* __restrict__ bias, void* __restrict__ Cp,
            const float* __restrict__ gate, float* __restrict__ partials,
            int M, int N, int K, int lda, int ldb, long bstride, int ldc,
            int nvalid)
{
  __shared__ unsigned short As[BM][LDT];   // A[m][k] tile
  __shared__ unsigned short Bs[BN][LDT];   // B^T: Bs[col][k]

  const int bx = blockIdx.x, by = blockIdx.y;
  const int t = threadIdx.x;
  const int lane = t & 63, wid = t >> 6;
  const int wr = wid >> 1, wc = wid & 1;       // wave -> 64x64 quadrant
  const int g = lane >> 4, r15 = lane & 15;

  facc4 acc[4][4];
#pragma unroll
  for (int m = 0; m < 4; m++)
#pragma unroll
    for (int n = 0; n < 4; n++) acc[m][n] = (facc4){0.f, 0.f, 0.f, 0.f};

  const float* Bblk = Bp + (long)bx * bstride;
  const int cv = nvalid - bx * BN;             // valid cols in this block

  const int a_r = t >> 1, a_k = (t & 1) * 16;  // A stage: 16 elems/thread
  const int b_c = (t & 15) * 8, b_k = t >> 4;  // B stage: 2 x 8 elems/thread
  const int rot = t & 7;                        // bank-conflict rotation

  for (int k0 = 0; k0 < K; k0 += BK) {
    // ---- stage A tile (row-major, contiguous 8-elem groups)
    if (ABF) {
      const unsigned short* Ag =
          (const unsigned short*)Ap + (long)(by * BM + a_r) * lda + k0 + a_k;
      uint4 v0 = *(const uint4*)(Ag);
      uint4 v1 = *(const uint4*)(Ag + 8);
      *(uint4*)&As[a_r][a_k] = v0;
      *(uint4*)&As[a_r][a_k + 8] = v1;
    } else {
      const float* Ag = (const float*)Ap + (long)(by * BM + a_r) * lda + k0 + a_k;
      unsigned short tmp[16];
#pragma unroll
      for (int i = 0; i < 16; i += 4) {
        facc4 v = *(const facc4*)(Ag + i);
        tmp[i] = f2bf(v[0]); tmp[i + 1] = f2bf(v[1]);
        tmp[i + 2] = f2bf(v[2]); tmp[i + 3] = f2bf(v[3]);
      }
      *(uint4*)&As[a_r][a_k] = *(uint4*)&tmp[0];
      *(uint4*)&As[a_r][a_k + 8] = *(uint4*)&tmp[8];
    }
    // ---- stage B tile transposed: Bs[col][k]
#pragma unroll
    for (int h = 0; h < 2; h++) {
      const int kr = b_k + h * 16;
      const float* Bg = Bblk + (long)(k0 + kr) * ldb + b_c;
      float v[8];
      if (b_c + 8 <= cv) {
        facc4 u0 = *(const facc4*)Bg;
        facc4 u1 = *(const facc4*)(Bg + 4);
        v[0] = u0[0]; v[1] = u0[1]; v[2] = u0[2]; v[3] = u0[3];
        v[4] = u1[0]; v[5] = u1[1]; v[6] = u1[2]; v[7] = u1[3];
      } else {
#pragma unroll
        for (int j = 0; j < 8; j++) v[j] = (b_c + j < cv) ? Bg[j] : 0.0f;
      }
      unsigned short b16[8];
#pragma unroll
      for (int j = 0; j < 8; j++) b16[j] = f2bf(v[j]);
#pragma unroll
      for (int jj = 0; jj < 8; jj++) {        // rotated scatter: spread banks
        int j = (jj + rot) & 7;
        Bs[b_c + j][kr] = b16[j];
      }
    }
    __syncthreads();
    // ---- compute: 4x4 grid of 16x16x32 MFMAs per wave
    bfrag8 af[4], bf[4];
#pragma unroll
    for (int m = 0; m < 4; m++)
      af[m] = *(const bfrag8*)&As[wr * 64 + m * 16 + r15][g * 8];
#pragma unroll
    for (int n = 0; n < 4; n++)
      bf[n] = *(const bfrag8*)&Bs[wc * 64 + n * 16 + r15][g * 8];
#pragma unroll
    for (int m = 0; m < 4; m++)
#pragma unroll
      for (int n = 0; n < 4; n++)
        acc[m][n] = __builtin_amdgcn_mfma_f32_16x16x32_bf16(af[m], bf[n],
                                                            acc[m][n], 0, 0, 0);
    __syncthreads();
  }

  // ---- epilogue. C/D frag layout: col=lane&15, row=(lane>>4)*4+reg.
  const int rbase = by * BM + wr * 64;
  const int cbase = bx * BN + wc * 64;

  if (EP == EP_PROJ) {
    unsigned short* C = (unsigned short*)Cp;
    float psum[4][4];
#pragma unroll
    for (int m = 0; m < 4; m++)
#pragma unroll
      for (int r = 0; r < 4; r++) psum[m][r] = 0.f;
#pragma unroll
    for (int m = 0; m < 4; m++)
#pragma unroll
      for (int n = 0; n < 4; n++)
#pragma unroll
        for (int r = 0; r < 4; r++) {
          int row = rbase + m * 16 + g * 4 + r;
          int col = cbase + n * 16 + r15;
          float val = acc[m][n][r] + bias[col];
          C[(long)row * ldc + col] = f2bf(val);
          psum[m][r] += val;
        }
#pragma unroll
    for (int m = 0; m < 4; m++)
#pragma unroll
      for (int r = 0; r < 4; r++) {
        float p = psum[m][r];
        p += __shfl_xor(p, 1); p += __shfl_xor(p, 2);
        p += __shfl_xor(p, 4); p += __shfl_xor(p, 8);
        if (r15 == 0)
          partials[(long)(rbase + m * 16 + g * 4 + r) * 32 + bx * 2 + wc] = p;
      }
  } else if (EP == EP_EXPERT) {
    unsigned short* C = (unsigned short*)Cp;
#pragma unroll
    for (int m = 0; m < 4; m++)
#pragma unroll
      for (int n = 0; n < 4; n++)
#pragma unroll
        for (int r = 0; r < 4; r++) {
          int row = rbase + m * 16 + g * 4 + r;
          int col = cbase + n * 16 + r15;
          float val = acc[m][n][r] + bias[col];
          val = fmaxf(val, 0.f) * gate[(long)row * 16 + (col >> 7)];
          C[(long)row * ldc + col] = f2bf(val);
        }
  } else if (EP == EP_CTX) {
    unsigned short* C = (unsigned short*)Cp;
#pragma unroll
    for (int m = 0; m < 4; m++)
#pragma unroll
      for (int n = 0; n < 4; n++)
#pragma unroll
        for (int r = 0; r < 4; r++) {
          int row = rbase + m * 16 + g * 4 + r;
          int col = cbase + n * 16 + r15;
          float val = acc[m][n][r] + bias[col];
          if (col < 20) val *= 2.0f;            // the entire "spiking attention"
          C[(long)row * ldc + col] = f2bf(val);
        }
  } else if (EP == EP_RELU) {
    unsigned short* C = (unsigned short*)Cp;
#pragma unroll
    for (int m = 0; m < 4; m++)
#pragma unroll
      for (int n = 0; n < 4; n++)
#pragma unroll
        for (int r = 0; r < 4; r++) {
          int row = rbase + m * 16 + g * 4 + r;
          int col = cbase + n * 16 + r15;
          float val = fmaxf(acc[m][n][r] + bias[col], 0.f);
          C[(long)row * ldc + col] = f2bf(val);
        }
  } else {  // EP_OUT: f32 store, masked cols
    float* C = (float*)Cp;
#pragma unroll
    for (int m = 0; m < 4; m++)
#pragma unroll
      for (int n = 0; n < 4; n++)
#pragma unroll
        for (int r = 0; r < 4; r++) {
          int row = rbase + m * 16 + g * 4 + r;
          int col = cbase + n * 16 + r15;
          if (col < nvalid)
            C[(long)row * ldc + col] = acc[m][n][r] + bias[col];
        }
  }
}

// t[b] = sum(partials[b][0..31]) / 2048 ; enh[b][2048+j] = sin/cos(7*t*harm)
__global__ void temporal_k(const float* __restrict__ partials,
                           unsigned short* __restrict__ enh)
{
  const int b = blockIdx.x;
  const int j = threadIdx.x;  // 128 threads
  float s = 0.f;
#pragma unroll
  for (int i = 0; i < 32; i++) s += partials[(long)b * 32 + i];
  float tmean = s * (1.0f / 2048.0f);
  float v;
  if (j < 64) v = sinf(7.0f * tmean * (float)(j + 1));
  else        v = cosf(7.0f * tmean * (float)(j - 63));
  enh[(long)b * 2176 + 2048 + j] = f2bf(v);
}

// gate = softmax(enh @ Wg + bg) over 16 experts; 16 rows x 16 experts / block
__global__ void gate_k(const unsigned short* __restrict__ enh,
                       const float* __restrict__ Wg,
                       const float* __restrict__ bg,
                       float* __restrict__ gate)
{
  const int t = threadIdx.x;
  const int r = t >> 4, e = t & 15;
  const long row = (long)blockIdx.x * 16 + r;
  const unsigned short* ep = enh + row * 2176;
  float acc = bg[e];
  for (int k = 0; k < 2176; k += 4) {
    ushort4 a = *(const ushort4*)(ep + k);
    acc += bf2f(a.x) * Wg[(k    ) * 16 + e];
    acc += bf2f(a.y) * Wg[(k + 1) * 16 + e];
    acc += bf2f(a.z) * Wg[(k + 2) * 16 + e];
    acc += bf2f(a.w) * Wg[(k + 3) * 16 + e];
  }
  float mx = acc;
  mx = fmaxf(mx, __shfl_xor(mx, 8)); mx = fmaxf(mx, __shfl_xor(mx, 4));
  mx = fmaxf(mx, __shfl_xor(mx, 2)); mx = fmaxf(mx, __shfl_xor(mx, 1));
  float ex = expf(acc - mx);
  float sum = ex;
  sum += __shfl_xor(sum, 8); sum += __shfl_xor(sum, 4);
  sum += __shfl_xor(sum, 2); sum += __shfl_xor(sum, 1);
  gate[row * 16 + e] = ex / sum;
}

// comb[b][k] = sum_e expw[b][e*128+k]   (gate & relu already applied)
__global__ void combine_k(const unsigned short* __restrict__ expw,
                          unsigned short* __restrict__ comb)
{
  const long i = (long)blockIdx.x * 256 + threadIdx.x;  // 8192*128 total
  const long b = i >> 7;
  const int k = (int)(i & 127);
  float s = 0.f;
#pragma unroll
  for (int e = 0; e < 16; e++) s += bf2f(expw[b * 2048 + e * 128 + k]);
  comb[i] = f2bf(s);
}

extern "C" void kernel_launch(void* const* d_in, const int* in_sizes, int n_in,
                              void* d_out, int out_size, void* d_ws,
                              size_t ws_size, hipStream_t stream)
{
  const float* x    = (const float*)d_in[0];
  const float* W_in = (const float*)d_in[1];
  const float* b_in = (const float*)d_in[2];
  const float* Wg   = (const float*)d_in[3];
  const float* bg   = (const float*)d_in[4];
  const float* We   = (const float*)d_in[5];
  const float* be   = (const float*)d_in[6];
  const float* Wo   = (const float*)d_in[7];
  const float* bo   = (const float*)d_in[8];
  const float* Wh   = (const float*)d_in[9];
  const float* bh   = (const float*)d_in[10];
  const float* Wcls = (const float*)d_in[11];
  const float* bcls = (const float*)d_in[12];
  float* out = (float*)d_out;

  char* ws = (char*)d_ws;
  unsigned short* enhb = (unsigned short*)ws;               // 8192*2176*2 = 35651584
  unsigned short* expw = (unsigned short*)(ws + 35651584);  // 8192*2048*2 = 33554432
  unsigned short* comb = (unsigned short*)(ws + 69206016);  // 8192*128*2  = 2097152
  float* partials = (float*)(ws + 71303168);                // 8192*32*4   = 1048576
  float* gate     = (float*)(ws + 72351744);                // 8192*16*4   = 524288
  // buffer reuse: attb -> enhb region; h1 -> expw; h2 -> enhb; h3 -> expw

  // 1) proj = x @ W_in + b_in  -> enhb[:, :2048] (bf16) + row partial sums
  gemm_k<false, EP_PROJ><<<dim3(16, 64), 256, 0, stream>>>(
      (const void*)x, W_in, b_in, (void*)enhb, nullptr, partials,
      8192, 2048, 1024, 1024, 2048, 128L, 2176, 2048);
  // 2) phasor bank -> enhb[:, 2048:2176]
  temporal_k<<<8192, 128, 0, stream>>>(partials, enhb);
  // 3) gate = softmax(enh @ Wg + bg)
  gate_k<<<512, 256, 0, stream>>>(enhb, Wg, bg, gate);
  // 4) expert: relu(enh @ We + be) * gate  (col block bx == expert e)
  gemm_k<true, EP_EXPERT><<<dim3(16, 64), 256, 0, stream>>>(
      (const void*)enhb, We, be, (void*)expw, gate, nullptr,
      8192, 2048, 2176, 2176, 128, 2176L * 128L, 2048, 2048);
  // 5) combined[b,k] = sum_e expw[b,e,k]
  combine_k<<<4096, 256, 0, stream>>>(expw, comb);
  // 6) context = comb @ Wo + bo ; double cols 0..19 -> attended (alias enhb)
  gemm_k<true, EP_CTX><<<dim3(16, 64), 256, 0, stream>>>(
      (const void*)comb, Wo, bo, (void*)enhb, nullptr, nullptr,
      8192, 2048, 128, 128, 2048, 128L, 2048, 2048);
  // 7) three relu MLP layers (ping-pong enhb <-> expw)
  gemm_k<true, EP_RELU><<<dim3(16, 64), 256, 0, stream>>>(
      (const void*)enhb, Wh, bh, (void*)expw, nullptr, nullptr,
      8192, 2048, 2048, 2048, 2048, 128L, 2048, 2048);
  gemm_k<true, EP_RELU><<<dim3(16, 64), 256, 0, stream>>>(
      (const void*)expw, Wh + 2048L * 2048L, bh + 2048, (void*)enhb, nullptr,
      nullptr, 8192, 2048, 2048, 2048, 2048, 128L, 2048, 2048);
  gemm_k<true, EP_RELU><<<dim3(16, 64), 256, 0, stream>>>(
      (const void*)enhb, Wh + 2L * 2048L * 2048L, bh + 4096, (void*)expw,
      nullptr, nullptr, 8192, 2048, 2048, 2048, 2048, 128L, 2048, 2048);
  // 8) logits = h3 @ Wcls + bcls  (N=1000 masked, f32 out)
  gemm_k<true, EP_OUT><<<dim3(8, 64), 256, 0, stream>>>(
      (const void*)expw, Wcls, bcls, (void*)out, nullptr, nullptr,
      8192, 1000, 2048, 2048, 1000, 128L, 1000, 1000);
}

// Round 2
// 592.731 us; speedup vs baseline: 2.5919x; 2.5919x over previous
//
#include <hip/hip_runtime.h>
#include <math.h>

// ---------------------------------------------------------------------------
// SophisticatedBioInspiredModel — bf16 MFMA, m97-structure GEMMs (gfx950).
//
// Spiking attention is data-independent: 100 distinct tokens, each bumped
// once from decayed-zero -> v=1.0 < 1.2 -> no spikes -> counts==0 ->
// top_k(zeros,20) = indices 0..19 -> gains double cols 0..19 of context.
//
// All GEMMs: C = A(MxK,bf16) * B^T(NxK,bf16) with 128x128 tile, BK=64,
// global_load_lds(16B) staging, T2 XOR swizzle (chunk ^= row&7 on 16B units),
// 16x16x32 bf16 MFMA, fused epilogues. Weights transposed+converted to bf16
// once per launch by an LDS-tiled transpose kernel (just-in-time, so the
// weight arenas rotate and the whole thing fits ~94.5 MB of workspace).
// ---------------------------------------------------------------------------

typedef unsigned short u16;
typedef __attribute__((ext_vector_type(8))) short bfrag8;   // 8 bf16
typedef __attribute__((ext_vector_type(4))) float facc4;    // 4 f32

__device__ __forceinline__ u16 f2bf(float f) {
  union { float f; unsigned u; } c; c.f = f;
  unsigned u = c.u;
  return (u16)((u + 0x7fffu + ((u >> 16) & 1u)) >> 16);
}
__device__ __forceinline__ float bf2f(u16 h) {
  union { unsigned u; float f; } c; c.u = ((unsigned)h) << 16;
  return c.f;
}

__device__ __forceinline__ void gload16(const void* g, void* lds) {
  __builtin_amdgcn_global_load_lds(
      (const __attribute__((address_space(1))) unsigned*)g,
      (__attribute__((address_space(3))) unsigned*)lds, 16, 0, 0);
}

enum { EP_PROJ = 0, EP_EXPERT = 1, EP_CTX = 2, EP_RELU = 3, EP_OUT = 4 };

// C = A(MxK) * Bt(NxK)^T. Grid: (N/128, M/128). K % 64 == 0, rows % 128 == 0.
// LDS layout: [row][chunk] 16B chunks, content swizzled chunk ^= (row&7);
// staged by global_load_lds with pre-swizzled global source (linear LDS dest).
template<bool AF32, int EP>
__global__ __launch_bounds__(256)
void gemm_bt(const void* __restrict__ Ap, const u16* __restrict__ Bt,
             const float* __restrict__ bias, void* __restrict__ Cp,
             const float* __restrict__ gate, float* __restrict__ partials,
             int K, int lda, int ldb, int ldc, int nvalid)
{
  __shared__ u16 As[128 * 64];
  __shared__ u16 Bs[128 * 64];

  const int t = threadIdx.x;
  const int lane = t & 63, wid = t >> 6;
  const int wr = wid >> 1, wc = wid & 1;
  const int g = lane >> 4, r15 = lane & 15;
  const int bx = blockIdx.x, by = blockIdx.y;

  facc4 acc[4][4];
#pragma unroll
  for (int m = 0; m < 4; m++)
#pragma unroll
    for (int n = 0; n < 4; n++) acc[m][n] = (facc4){0.f, 0.f, 0.f, 0.f};

  const u16* Ab = (const u16*)Ap;
  const float* Af = (const float*)Ap;
  const long a_base = (long)(by * 128) * lda;
  const long b_base = (long)(bx * 128) * ldb;

  const int srow = t >> 3;      // staging row within 32-row group
  const int schunk = t & 7;     // staging 16B chunk within row
  char* AsB = (char*)As;
  char* BsB = (char*)Bs;

  for (int k0 = 0; k0 < K; k0 += 64) {
    // ---- stage A
    if (!AF32) {
#pragma unroll
      for (int j = 0; j < 4; j++) {
        int row = j * 32 + srow;
        const u16* src = Ab + a_base + (long)row * lda + k0 +
                         ((schunk ^ (row & 7)) << 3);
        gload16(src, AsB + (wid << 10) + j * 4096);
      }
    } else {
      int row = t >> 1;
      int kh = (t & 1) << 5;
      const float* src = Af + a_base + (long)row * lda + k0 + kh;
      u16 tmp[32];
#pragma unroll
      for (int i = 0; i < 32; i += 4) {
        facc4 v = *(const facc4*)(src + i);
        tmp[i] = f2bf(v[0]); tmp[i + 1] = f2bf(v[1]);
        tmp[i + 2] = f2bf(v[2]); tmp[i + 3] = f2bf(v[3]);
      }
#pragma unroll
      for (int c = 0; c < 4; c++) {
        int chunk = (kh >> 3) + c;
        *(uint4*)(AsB + row * 128 + ((chunk ^ (row & 7)) << 4)) =
            ((const uint4*)tmp)[c];
      }
    }
    // ---- stage B
#pragma unroll
    for (int j = 0; j < 4; j++) {
      int row = j * 32 + srow;
      const u16* src = Bt + b_base + (long)row * ldb + k0 +
                       ((schunk ^ (row & 7)) << 3);
      gload16(src, BsB + (wid << 10) + j * 4096);
    }
    __syncthreads();
    // ---- compute
#pragma unroll
    for (int ks = 0; ks < 2; ks++) {
      bfrag8 af[4], bf[4];
#pragma unroll
      for (int m = 0; m < 4; m++) {
        int row = wr * 64 + m * 16 + r15;
        af[m] = *(const bfrag8*)(AsB + row * 128 +
                                 (((g + ks * 4) ^ (row & 7)) << 4));
      }
#pragma unroll
      for (int n = 0; n < 4; n++) {
        int row = wc * 64 + n * 16 + r15;
        bf[n] = *(const bfrag8*)(BsB + row * 128 +
                                 (((g + ks * 4) ^ (row & 7)) << 4));
      }
#pragma unroll
      for (int m = 0; m < 4; m++)
#pragma unroll
        for (int n = 0; n < 4; n++)
          acc[m][n] = __builtin_amdgcn_mfma_f32_16x16x32_bf16(
              af[m], bf[n], acc[m][n], 0, 0, 0);
    }
    __syncthreads();
  }

  // ---- epilogue. C/D layout: col=lane&15, row=(lane>>4)*4+reg.
  const int rbase = by * 128 + wr * 64;
  const int cbase = bx * 128 + wc * 64;

  if (EP == EP_PROJ) {
    u16* C = (u16*)Cp;
    float psum[4][4];
#pragma unroll
    for (int m = 0; m < 4; m++)
#pragma unroll
      for (int r = 0; r < 4; r++) psum[m][r] = 0.f;
#pragma unroll
    for (int m = 0; m < 4; m++)
#pragma unroll
      for (int n = 0; n < 4; n++)
#pragma unroll
        for (int r = 0; r < 4; r++) {
          int row = rbase + m * 16 + g * 4 + r;
          int col = cbase + n * 16 + r15;
          float val = acc[m][n][r] + bias[col];
          C[(long)row * ldc + col] = f2bf(val);
          psum[m][r] += val;
        }
#pragma unroll
    for (int m = 0; m < 4; m++)
#pragma unroll
      for (int r = 0; r < 4; r++) {
        float p = psum[m][r];
        p += __shfl_xor(p, 1); p += __shfl_xor(p, 2);
        p += __shfl_xor(p, 4); p += __shfl_xor(p, 8);
        if (r15 == 0)
          partials[(long)(rbase + m * 16 + g * 4 + r) * 32 + bx * 2 + wc] = p;
      }
  } else if (EP == EP_EXPERT) {
    u16* C = (u16*)Cp;
#pragma unroll
    for (int m = 0; m < 4; m++)
#pragma unroll
      for (int n = 0; n < 4; n++)
#pragma unroll
        for (int r = 0; r < 4; r++) {
          int row = rbase + m * 16 + g * 4 + r;
          int col = cbase + n * 16 + r15;
          float val = acc[m][n][r] + bias[col];
          val = fmaxf(val, 0.f) * gate[(long)row * 16 + (col >> 7)];
          C[(long)row * ldc + col] = f2bf(val);
        }
  } else if (EP == EP_CTX) {
    u16* C = (u16*)Cp;
#pragma unroll
    for (int m = 0; m < 4; m++)
#pragma unroll
      for (int n = 0; n < 4; n++)
#pragma unroll
        for (int r = 0; r < 4; r++) {
          int row = rbase + m * 16 + g * 4 + r;
          int col = cbase + n * 16 + r15;
          float val = acc[m][n][r] + bias[col];
          if (col < 20) val *= 2.0f;            // entire spiking attention
          C[(long)row * ldc + col] = f2bf(val);
        }
  } else if (EP == EP_RELU) {
    u16* C = (u16*)Cp;
#pragma unroll
    for (int m = 0; m < 4; m++)
#pragma unroll
      for (int n = 0; n < 4; n++)
#pragma unroll
        for (int r = 0; r < 4; r++) {
          int row = rbase + m * 16 + g * 4 + r;
          int col = cbase + n * 16 + r15;
          C[(long)row * ldc + col] = f2bf(fmaxf(acc[m][n][r] + bias[col], 0.f));
        }
  } else {  // EP_OUT
    float* C = (float*)Cp;
#pragma unroll
    for (int m = 0; m < 4; m++)
#pragma unroll
      for (int n = 0; n < 4; n++)
#pragma unroll
        for (int r = 0; r < 4; r++) {
          int row = rbase + m * 16 + g * 4 + r;
          int col = cbase + n * 16 + r15;
          if (col < nvalid)
            C[(long)row * ldc + col] = acc[m][n][r] + bias[col];
        }
  }
}

// out[n][k] = bf16(in[k][n]) for one z-slice; 64x64 LDS tile.
// Pads out rows n >= N with zeros (for Wcls). Grid: (ceil(N/64), K/64, Z).
__global__ __launch_bounds__(256)
void transpose_conv_k(const float* __restrict__ in, u16* __restrict__ out,
                      int K, int N, int ldout, long in_zstride, int out_zrows)
{
  __shared__ float tile[64][65];
  const int t = threadIdx.x;
  const int n0 = blockIdx.x * 64, k0 = blockIdx.y * 64;
  const float* src = in + (long)blockIdx.z * in_zstride;

  const int rr = t >> 4;            // 16 rows per pass
  const int cc = (t & 15) * 4;
#pragma unroll
  for (int j = 0; j < 4; j++) {
    int k = k0 + j * 16 + rr;
    int n = n0 + cc;
    float v0 = 0.f, v1 = 0.f, v2 = 0.f, v3 = 0.f;
    if (n + 3 < N) {
      facc4 v = *(const facc4*)(src + (long)k * N + n);
      v0 = v[0]; v1 = v[1]; v2 = v[2]; v3 = v[3];
    } else {
      if (n < N)     v0 = src[(long)k * N + n];
      if (n + 1 < N) v1 = src[(long)k * N + n + 1];
      if (n + 2 < N) v2 = src[(long)k * N + n + 2];
      if (n + 3 < N) v3 = src[(long)k * N + n + 3];
    }
    float* trow = &tile[j * 16 + rr][cc];
    trow[0] = v0; trow[1] = v1; trow[2] = v2; trow[3] = v3;
  }
  __syncthreads();
  const int n_l = t >> 2;
  const int kc = (t & 3) * 16;
  const int n_gl = n0 + n_l;
  u16 o16[16];
  const bool valid = n_gl < N;
#pragma unroll
  for (int i = 0; i < 16; i++) o16[i] = valid ? f2bf(tile[kc + i][n_l]) : (u16)0;
  long orow = (long)blockIdx.z * out_zrows + n_gl;
  u16* dst = out + orow * (long)ldout + k0 + kc;
  *(uint4*)dst = ((const uint4*)o16)[0];
  *(uint4*)(dst + 8) = ((const uint4*)o16)[1];
}

// t[b] = sum(partials[b][:])/2048 ; enh[b][2048+j] = sin/cos(7*t*harm)
__global__ void temporal_k(const float* __restrict__ partials,
                           u16* __restrict__ enh)
{
  const int b = blockIdx.x;
  const int j = threadIdx.x;  // 128
  float s = 0.f;
#pragma unroll
  for (int i = 0; i < 32; i++) s += partials[(long)b * 32 + i];
  float tmean = s * (1.0f / 2048.0f);
  float v;
  if (j < 64) v = sinf(7.0f * tmean * (float)(j + 1));
  else        v = cosf(7.0f * tmean * (float)(j - 63));
  enh[(long)b * 2176 + 2048 + j] = f2bf(v);
}

// gate = softmax(enh @ Wg + bg); 16 rows x 16 experts per block
__global__ void gate_k(const u16* __restrict__ enh, const float* __restrict__ Wg,
                       const float* __restrict__ bg, float* __restrict__ gate)
{
  const int t = threadIdx.x;
  const int r = t >> 4, e = t & 15;
  const long row = (long)blockIdx.x * 16 + r;
  const u16* ep = enh + row * 2176;
  float acc = bg[e];
  for (int k = 0; k < 2176; k += 4) {
    ushort4 a = *(const ushort4*)(ep + k);
    acc += bf2f(a.x) * Wg[(k    ) * 16 + e];
    acc += bf2f(a.y) * Wg[(k + 1) * 16 + e];
    acc += bf2f(a.z) * Wg[(k + 2) * 16 + e];
    acc += bf2f(a.w) * Wg[(k + 3) * 16 + e];
  }
  float mx = acc;
  mx = fmaxf(mx, __shfl_xor(mx, 8)); mx = fmaxf(mx, __shfl_xor(mx, 4));
  mx = fmaxf(mx, __shfl_xor(mx, 2)); mx = fmaxf(mx, __shfl_xor(mx, 1));
  float ex = expf(acc - mx);
  float sum = ex;
  sum += __shfl_xor(sum, 8); sum += __shfl_xor(sum, 4);
  sum += __shfl_xor(sum, 2); sum += __shfl_xor(sum, 1);
  gate[row * 16 + e] = ex / sum;
}

// comb[b][k] = sum_e expw[b][e*128+k]
__global__ void combine_k(const u16* __restrict__ expw, u16* __restrict__ comb)
{
  const long i = (long)blockIdx.x * 256 + threadIdx.x;
  const long b = i >> 7;
  const int k = (int)(i & 127);
  float s = 0.f;
#pragma unroll
  for (int e = 0; e < 16; e++) s += bf2f(expw[b * 2048 + e * 128 + k]);
  comb[i] = f2bf(s);
}

extern "C" void kernel_launch(void* const* d_in, const int* in_sizes, int n_in,
                              void* d_out, int out_size, void* d_ws,
                              size_t ws_size, hipStream_t stream)
{
  const float* x    = (const float*)d_in[0];
  const float* W_in = (const float*)d_in[1];
  const float* b_in = (const float*)d_in[2];
  const float* Wg   = (const float*)d_in[3];
  const float* bg   = (const float*)d_in[4];
  const float* We   = (const float*)d_in[5];
  const float* be   = (const float*)d_in[6];
  const float* Wo   = (const float*)d_in[7];
  const float* bo   = (const float*)d_in[8];
  const float* Wh   = (const float*)d_in[9];
  const float* bh   = (const float*)d_in[10];
  const float* Wcls = (const float*)d_in[11];
  const float* bcls = (const float*)d_in[12];
  float* out = (float*)d_out;

  char* ws = (char*)d_ws;
  u16* enhb   = (u16*)(ws);                    // 35,651,584  [8192][2176] bf16
  u16* bufF   = (u16*)(ws + 35651584);         // 33,554,432  Wt_in -> expw/h1/h3
  u16* bufA   = (u16*)(ws + 69206016);         //  8,912,896  Wt_e -> Wt_cls
  u16* Wt_o   = (u16*)(ws + 78118912);         //    524,288  [2048][128]
  u16* bufW1  = (u16*)(ws + 78643200);         //  8,388,608  Wh0 -> Wh2
  u16* bufW2  = (u16*)(ws + 87031808);         //  8,388,608  Wh1
  u16* comb   = (u16*)(ws + 95420416);         //  2,097,152  [8192][128]
  float* partials = (float*)(ws + 97517568);   //  1,048,576
  float* gate     = (float*)(ws + 98566144);   //    524,288
  u16* Wt_in  = bufF;                          // [2048][1024], dead after proj
  u16* Wt_e   = bufA;                          // [2048][2176], dead after expert
  u16* Wt_cls = bufA;                          // [1024][2048], converted later

  // ---- weight transposes (f32 KxN -> bf16 NxK) needed before first GEMMs
  transpose_conv_k<<<dim3(32, 16, 1), 256, 0, stream>>>(W_in, Wt_in, 1024, 2048, 1024, 0, 0);
  transpose_conv_k<<<dim3(2, 34, 16), 256, 0, stream>>>(We, Wt_e, 2176, 128, 2176, 2176L * 128L, 128);
  transpose_conv_k<<<dim3(32, 2, 1), 256, 0, stream>>>(Wo, Wt_o, 128, 2048, 128, 0, 0);
  transpose_conv_k<<<dim3(32, 32, 1), 256, 0, stream>>>(Wh, bufW1, 2048, 2048, 2048, 0, 0);
  transpose_conv_k<<<dim3(32, 32, 1), 256, 0, stream>>>(Wh + 2048L * 2048L, bufW2, 2048, 2048, 2048, 0, 0);

  // 1) proj = x @ W_in + b_in -> enhb[:, :2048] + row partial sums
  gemm_bt<true, EP_PROJ><<<dim3(16, 64), 256, 0, stream>>>(
      (const void*)x, Wt_in, b_in, (void*)enhb, nullptr, partials,
      1024, 1024, 1024, 2176, 2048);
  // 2) phasor bank -> enhb[:, 2048:]
  temporal_k<<<8192, 128, 0, stream>>>(partials, enhb);
  // 3) softmax gate
  gate_k<<<512, 256, 0, stream>>>(enhb, Wg, bg, gate);
  // 4) experts: relu(enh @ We + be) * gate  (col-block bx == expert)
  gemm_bt<false, EP_EXPERT><<<dim3(16, 64), 256, 0, stream>>>(
      (const void*)enhb, Wt_e, be, (void*)bufF, gate, nullptr,
      2176, 2176, 2176, 2048, 2048);
  // Wt_e dead -> convert Wcls into bufA
  transpose_conv_k<<<dim3(16, 32, 1), 256, 0, stream>>>(Wcls, Wt_cls, 2048, 1000, 2048, 0, 0);
  // 5) combine experts
  combine_k<<<4096, 256, 0, stream>>>(bufF, comb);
  // 6) context = comb @ Wo + bo, cols<20 doubled -> attended (enhb region)
  gemm_bt<false, EP_CTX><<<dim3(16, 64), 256, 0, stream>>>(
      (const void*)comb, Wt_o, bo, (void*)enhb, nullptr, nullptr,
      128, 128, 128, 2048, 2048);
  // 7) MLP: h1 -> bufF, h2 -> enhb, h3 -> bufF
  gemm_bt<false, EP_RELU><<<dim3(16, 64), 256, 0, stream>>>(
      (const void*)enhb, bufW1, bh, (void*)bufF, nullptr, nullptr,
      2048, 2048, 2048, 2048, 2048);
  // Wh0 dead -> convert Wh2 into bufW1
  transpose_conv_k<<<dim3(32, 32, 1), 256, 0, stream>>>(Wh + 2L * 2048L * 2048L, bufW1, 2048, 2048, 2048, 0, 0);
  gemm_bt<false, EP_RELU><<<dim3(16, 64), 256, 0, stream>>>(
      (const void*)bufF, bufW2, bh + 2048, (void*)enhb, nullptr, nullptr,
      2048, 2048, 2048, 2048, 2048);
  gemm_bt<false, EP_RELU><<<dim3(16, 64), 256, 0, stream>>>(
      (const void*)enhb, bufW1, bh + 4096, (void*)bufF, nullptr, nullptr,
      2048, 2048, 2048, 2048, 2048);
  // 8) logits (N=1000, padded Bt rows are zero; stores masked)
  gemm_bt<false, EP_OUT><<<dim3(8, 64), 256, 0, stream>>>(
      (const void*)bufF, Wt_cls, bcls, (void*)out, nullptr, nullptr,
      2048, 2048, 2048, 1000, 1000);
}

// Round 3
// 449.712 us; speedup vs baseline: 3.4161x; 1.3180x over previous
//
#include <hip/hip_runtime.h>
#include <math.h>

// ---------------------------------------------------------------------------
// SophisticatedBioInspiredModel — bf16 MFMA, 256^2 8-phase GEMMs (gfx950).
//
// Spiking attention is data-independent: 100 distinct tokens, each bumped once
// from decayed-zero -> v=1.0 < 1.2 -> no spikes -> counts==0 -> top_k(zeros,20)
// = indices 0..19 -> gains double cols 0..19 of context.
//
// GEMM: C = A(MxK,bf16) * Bt(NxK,bf16)^T. 256x256 tile, BK=64, 8 waves (2Mx4N),
// 128 KiB LDS double-buffer, 8-phase schedule with counted vmcnt(4) (never 0
// in the main loop), chunk^(row&7) 16B-swizzle (0 bank conflicts, verified),
// setprio around MFMA clusters, bijective XCD block swizzle.
// ---------------------------------------------------------------------------

typedef unsigned short u16;
typedef __attribute__((ext_vector_type(8))) short bfrag8;
typedef __attribute__((ext_vector_type(4))) float facc4;

__device__ __forceinline__ u16 f2bf(float f) {
  union { float f; unsigned u; } c; c.f = f;
  unsigned u = c.u;
  return (u16)((u + 0x7fffu + ((u >> 16) & 1u)) >> 16);
}
__device__ __forceinline__ float bf2f(u16 h) {
  union { unsigned u; float f; } c; c.u = ((unsigned)h) << 16;
  return c.f;
}
__device__ __forceinline__ void gload16(const void* g, void* lds) {
  __builtin_amdgcn_global_load_lds(
      (const __attribute__((address_space(1))) unsigned*)g,
      (__attribute__((address_space(3))) unsigned*)lds, 16, 0, 0);
}

#define BARX() do { __builtin_amdgcn_sched_barrier(0); \
  __builtin_amdgcn_s_barrier(); __builtin_amdgcn_sched_barrier(0); } while (0)
#define LGKM0() do { asm volatile("s_waitcnt lgkmcnt(0)" ::: "memory"); \
  __builtin_amdgcn_sched_barrier(0); } while (0)
#define VMW4() do { asm volatile("s_waitcnt vmcnt(4)" ::: "memory"); \
  __builtin_amdgcn_sched_barrier(0); } while (0)

#define RDA_(dst, mbase, dbuf) do { \
  char* _b = smem + (dbuf) * 65536; \
  _Pragma("unroll") for (int mm = 0; mm < 4; ++mm) { \
    int _row = wr * 128 + ((mbase) + mm) * 16 + r15; \
    _Pragma("unroll") for (int ks = 0; ks < 2; ++ks) \
      dst[mm][ks] = *(const bfrag8*)(_b + _row * 128 + \
                                     (((g + ks * 4) ^ (_row & 7)) << 4)); \
  } } while (0)

#define RDB_(dst, nbase, dbuf) do { \
  char* _b = smem + (dbuf) * 65536 + 32768; \
  _Pragma("unroll") for (int nn = 0; nn < 2; ++nn) { \
    int _row = wc * 64 + ((nbase) + nn) * 16 + r15; \
    _Pragma("unroll") for (int ks = 0; ks < 2; ++ks) \
      dst[nn][ks] = *(const bfrag8*)(_b + _row * 128 + \
                                     (((g + ks * 4) ^ (_row & 7)) << 4)); \
  } } while (0)

#define MF_(a, b, mo, no) do { \
  __builtin_amdgcn_s_setprio(1); \
  _Pragma("unroll") for (int mm = 0; mm < 4; ++mm) \
  _Pragma("unroll") for (int nn = 0; nn < 2; ++nn) \
  _Pragma("unroll") for (int ks = 0; ks < 2; ++ks) \
    acc[(mo) + mm][(no) + nn] = __builtin_amdgcn_mfma_f32_16x16x32_bf16( \
        a[mm][ks], b[nn][ks], acc[(mo) + mm][(no) + nn], 0, 0, 0); \
  __builtin_amdgcn_s_setprio(0); \
} while (0)

enum { EP_PROJ = 0, EP_EXPERT = 1, EP_CTX = 2, EP_RELU = 3, EP_OUT = 4 };

// Grid: (N/256, M/256). K%64==0, K/64 even and >=2. A rows %256==0, Bt rows %256==0.
template<int EP>
__global__ __launch_bounds__(512, 2)
void gemm8(const u16* __restrict__ A, const u16* __restrict__ Bt,
           const float* __restrict__ bias, void* __restrict__ Cp,
           const float* __restrict__ gate, float* __restrict__ partials,
           int K, int lda, int ldb, int ldc, int nvalid)
{
  extern __shared__ char smem[];   // 131072 B: [dbuf][A 32K | B 32K]
  const int t = threadIdx.x;
  const int lane = t & 63, wid = t >> 6;
  const int wr = wid >> 2, wc = wid & 3;
  const int g = lane >> 4, r15 = lane & 15;

  // bijective XCD swizzle (nblk % 8 == 0 for all our grids)
  const int nblk = gridDim.x * gridDim.y;
  const int flat = blockIdx.y * gridDim.x + blockIdx.x;
  const int swz = (flat & 7) * (nblk >> 3) + (flat >> 3);
  const int bx = swz % gridDim.x, by = swz / gridDim.x;

  const long a0 = (long)(by * 256) * lda;
  const long b0 = (long)(bx * 256) * ldb;

  facc4 acc[8][4];
#pragma unroll
  for (int m = 0; m < 8; m++)
#pragma unroll
    for (int n = 0; n < 4; n++) acc[m][n] = (facc4){0.f, 0.f, 0.f, 0.f};

  const int r0 = t >> 3, c0 = t & 7;
  const int csw = ((c0 ^ (r0 & 7)) << 3);   // swizzled k-chunk (elems)

  // which: 0=A-half0, 1=A-half1, 2=B-half0, 3=B-half1
  auto STAGE = [&](int kt, int which, int dbuf) {
    const int half = which & 1;
    const u16* gsrc;
    int ld;
    char* ldst = smem + dbuf * 65536 + half * 16384;
    if (which < 2) { gsrc = A + a0; ld = lda; }
    else           { gsrc = Bt + b0; ld = ldb; ldst += 32768; }
    gsrc += (long)(half * 128 + r0) * ld + kt * 64 + csw;
    gload16(gsrc, ldst + (t << 4));
    gload16(gsrc + 64L * ld, ldst + ((512 + t) << 4));
  };

  const int NT = K >> 6;
  // prologue: tile0 fully, tile1 A-halves. vmcnt(4) leaves tile1.A in flight.
  STAGE(0, 0, 0); STAGE(0, 1, 0); STAGE(0, 2, 0); STAGE(0, 3, 0);
  STAGE(1, 0, 1); STAGE(1, 1, 1);
  VMW4(); BARX();

  bfrag8 aE[4][2], aO[4][2], b01[2][2], b23[2][2];

  for (int it = 0; it < (NT >> 1); ++it) {
    const int T = 2 * it;
    const int tp1 = T + 1;
    const int tp2 = (T + 2 < NT) ? T + 2 : NT - 1;
    const int tp3 = (T + 3 < NT) ? T + 3 : NT - 1;
    // p1: consume buf0(T) quadrant (m0-3 x n0-1); stage (T+1).B0 -> buf1
    RDA_(aE, 0, 0); RDB_(b01, 0, 0); STAGE(tp1, 2, 1);
    BARX(); LGKM0(); MF_(aE, b01, 0, 0); BARX();
    // p2
    RDA_(aO, 4, 0); STAGE(tp1, 3, 1);
    BARX(); LGKM0(); MF_(aO, b01, 4, 0); BARX();
    // p3
    RDB_(b23, 2, 0); STAGE(tp2, 0, 0);
    BARX(); LGKM0(); MF_(aO, b23, 4, 2); BARX();
    // p4: vmcnt(4) -> (T+1) fully landed before p5 reads buf1
    STAGE(tp2, 1, 0); VMW4();
    BARX(); MF_(aE, b23, 0, 2); BARX();
    // p5: consume buf1(T+1); stage (T+2).B0 -> buf0
    RDA_(aE, 0, 1); RDB_(b01, 0, 1); STAGE(tp2, 2, 0);
    BARX(); LGKM0(); MF_(aE, b01, 0, 0); BARX();
    // p6
    RDA_(aO, 4, 1); STAGE(tp2, 3, 0);
    BARX(); LGKM0(); MF_(aO, b01, 4, 0); BARX();
    // p7
    RDB_(b23, 2, 1); STAGE(tp3, 0, 1);
    BARX(); LGKM0(); MF_(aO, b23, 4, 2); BARX();
    // p8: vmcnt(4) -> (T+2) fully landed before next p1 reads buf0
    STAGE(tp3, 1, 1); VMW4();
    BARX(); MF_(aE, b23, 0, 2); BARX();
  }

  // ---- epilogue. C/D layout: col=lane&15, row=(lane>>4)*4+reg.
  const int rbase = by * 256 + wr * 128;
  const int cbase = bx * 256 + wc * 64;

  if (EP == EP_PROJ) {
    u16* C = (u16*)Cp;
    float psum[8][4];
#pragma unroll
    for (int m = 0; m < 8; m++)
#pragma unroll
      for (int r = 0; r < 4; r++) psum[m][r] = 0.f;
#pragma unroll
    for (int m = 0; m < 8; m++)
#pragma unroll
      for (int n = 0; n < 4; n++)
#pragma unroll
        for (int r = 0; r < 4; r++) {
          int row = rbase + m * 16 + g * 4 + r;
          int col = cbase + n * 16 + r15;
          float val = acc[m][n][r] + bias[col];
          C[(long)row * ldc + col] = f2bf(val);
          psum[m][r] += val;
        }
#pragma unroll
    for (int m = 0; m < 8; m++)
#pragma unroll
      for (int r = 0; r < 4; r++) {
        float p = psum[m][r];
        p += __shfl_xor(p, 1); p += __shfl_xor(p, 2);
        p += __shfl_xor(p, 4); p += __shfl_xor(p, 8);
        if (r15 == 0)
          partials[(long)(rbase + m * 16 + g * 4 + r) * 32 + bx * 4 + wc] = p;
      }
  } else if (EP == EP_EXPERT) {
    u16* C = (u16*)Cp;
#pragma unroll
    for (int m = 0; m < 8; m++)
#pragma unroll
      for (int n = 0; n < 4; n++)
#pragma unroll
        for (int r = 0; r < 4; r++) {
          int row = rbase + m * 16 + g * 4 + r;
          int col = cbase + n * 16 + r15;
          float val = acc[m][n][r] + bias[col];
          val = fmaxf(val, 0.f) * gate[(long)row * 16 + (col >> 7)];
          C[(long)row * ldc + col] = f2bf(val);
        }
  } else if (EP == EP_CTX) {
    u16* C = (u16*)Cp;
#pragma unroll
    for (int m = 0; m < 8; m++)
#pragma unroll
      for (int n = 0; n < 4; n++)
#pragma unroll
        for (int r = 0; r < 4; r++) {
          int row = rbase + m * 16 + g * 4 + r;
          int col = cbase + n * 16 + r15;
          float val = acc[m][n][r] + bias[col];
          if (col < 20) val *= 2.0f;            // entire spiking attention
          C[(long)row * ldc + col] = f2bf(val);
        }
  } else if (EP == EP_RELU) {
    u16* C = (u16*)Cp;
#pragma unroll
    for (int m = 0; m < 8; m++)
#pragma unroll
      for (int n = 0; n < 4; n++)
#pragma unroll
        for (int r = 0; r < 4; r++) {
          int row = rbase + m * 16 + g * 4 + r;
          int col = cbase + n * 16 + r15;
          C[(long)row * ldc + col] = f2bf(fmaxf(acc[m][n][r] + bias[col], 0.f));
        }
  } else {  // EP_OUT
    float* C = (float*)Cp;
#pragma unroll
    for (int m = 0; m < 8; m++)
#pragma unroll
      for (int n = 0; n < 4; n++)
#pragma unroll
        for (int r = 0; r < 4; r++) {
          int row = rbase + m * 16 + g * 4 + r;
          int col = cbase + n * 16 + r15;
          if (col < nvalid)
            C[(long)row * ldc + col] = acc[m][n][r] + bias[col];
        }
  }
}

// out[n][k] = bf16(in[k][n]); pads rows n>=N with zeros. Grid: (ceil(N/64), K/64, Z).
__global__ __launch_bounds__(256)
void transpose_conv_k(const float* __restrict__ in, u16* __restrict__ out,
                      int K, int N, int ldout, long in_zstride, int out_zrows)
{
  __shared__ float tile[64][65];
  const int t = threadIdx.x;
  const int n0 = blockIdx.x * 64, k0 = blockIdx.y * 64;
  const float* src = in + (long)blockIdx.z * in_zstride;
  const int rr = t >> 4;
  const int cc = (t & 15) * 4;
#pragma unroll
  for (int j = 0; j < 4; j++) {
    int k = k0 + j * 16 + rr;
    int n = n0 + cc;
    float v0 = 0.f, v1 = 0.f, v2 = 0.f, v3 = 0.f;
    if (n + 3 < N) {
      facc4 v = *(const facc4*)(src + (long)k * N + n);
      v0 = v[0]; v1 = v[1]; v2 = v[2]; v3 = v[3];
    } else {
      if (n < N)     v0 = src[(long)k * N + n];
      if (n + 1 < N) v1 = src[(long)k * N + n + 1];
      if (n + 2 < N) v2 = src[(long)k * N + n + 2];
      if (n + 3 < N) v3 = src[(long)k * N + n + 3];
    }
    float* trow = &tile[j * 16 + rr][cc];
    trow[0] = v0; trow[1] = v1; trow[2] = v2; trow[3] = v3;
  }
  __syncthreads();
  const int n_l = t >> 2;
  const int kc = (t & 3) * 16;
  const int n_gl = n0 + n_l;
  u16 o16[16];
  const bool valid = n_gl < N;
#pragma unroll
  for (int i = 0; i < 16; i++) o16[i] = valid ? f2bf(tile[kc + i][n_l]) : (u16)0;
  long orow = (long)blockIdx.z * out_zrows + n_gl;
  u16* dst = out + orow * (long)ldout + k0 + kc;
  *(uint4*)dst = ((const uint4*)o16)[0];
  *(uint4*)(dst + 8) = ((const uint4*)o16)[1];
}

__global__ __launch_bounds__(256)
void f32_to_bf16_k(const float* __restrict__ in, u16* __restrict__ out)
{
  const long i = ((long)blockIdx.x * 256 + threadIdx.x) * 8;
  facc4 v0 = *(const facc4*)(in + i);
  facc4 v1 = *(const facc4*)(in + i + 4);
  u16 o[8];
  o[0] = f2bf(v0[0]); o[1] = f2bf(v0[1]); o[2] = f2bf(v0[2]); o[3] = f2bf(v0[3]);
  o[4] = f2bf(v1[0]); o[5] = f2bf(v1[1]); o[6] = f2bf(v1[2]); o[7] = f2bf(v1[3]);
  *(uint4*)(out + i) = *(const uint4*)o;
}

__global__ void temporal_k(const float* __restrict__ partials,
                           u16* __restrict__ enh)
{
  const int b = blockIdx.x;
  const int j = threadIdx.x;  // 128
  float s = 0.f;
#pragma unroll
  for (int i = 0; i < 32; i++) s += partials[(long)b * 32 + i];
  float tmean = s * (1.0f / 2048.0f);
  float v;
  if (j < 64) v = sinf(7.0f * tmean * (float)(j + 1));
  else        v = cosf(7.0f * tmean * (float)(j - 63));
  enh[(long)b * 2176 + 2048 + j] = f2bf(v);
}

__global__ void gate_k(const u16* __restrict__ enh, const float* __restrict__ Wg,
                       const float* __restrict__ bg, float* __restrict__ gate)
{
  const int t = threadIdx.x;
  const int r = t >> 4, e = t & 15;
  const long row = (long)blockIdx.x * 16 + r;
  const u16* ep = enh + row * 2176;
  float acc = bg[e];
  for (int k = 0; k < 2176; k += 4) {
    ushort4 a = *(const ushort4*)(ep + k);
    acc += bf2f(a.x) * Wg[(k    ) * 16 + e];
    acc += bf2f(a.y) * Wg[(k + 1) * 16 + e];
    acc += bf2f(a.z) * Wg[(k + 2) * 16 + e];
    acc += bf2f(a.w) * Wg[(k + 3) * 16 + e];
  }
  float mx = acc;
  mx = fmaxf(mx, __shfl_xor(mx, 8)); mx = fmaxf(mx, __shfl_xor(mx, 4));
  mx = fmaxf(mx, __shfl_xor(mx, 2)); mx = fmaxf(mx, __shfl_xor(mx, 1));
  float ex = expf(acc - mx);
  float sum = ex;
  sum += __shfl_xor(sum, 8); sum += __shfl_xor(sum, 4);
  sum += __shfl_xor(sum, 2); sum += __shfl_xor(sum, 1);
  gate[row * 16 + e] = ex / sum;
}

__global__ void combine_k(const u16* __restrict__ expw, u16* __restrict__ comb)
{
  const long i = (long)blockIdx.x * 256 + threadIdx.x;
  const long b = i >> 7;
  const int k = (int)(i & 127);
  float s = 0.f;
#pragma unroll
  for (int e = 0; e < 16; e++) s += bf2f(expw[b * 2048 + e * 128 + k]);
  comb[i] = f2bf(s);
}

extern "C" void kernel_launch(void* const* d_in, const int* in_sizes, int n_in,
                              void* d_out, int out_size, void* d_ws,
                              size_t ws_size, hipStream_t stream)
{
  const float* x    = (const float*)d_in[0];
  const float* W_in = (const float*)d_in[1];
  const float* b_in = (const float*)d_in[2];
  const float* Wg   = (const float*)d_in[3];
  const float* bg   = (const float*)d_in[4];
  const float* We   = (const float*)d_in[5];
  const float* be   = (const float*)d_in[6];
  const float* Wo   = (const float*)d_in[7];
  const float* bo   = (const float*)d_in[8];
  const float* Wh   = (const float*)d_in[9];
  const float* bh   = (const float*)d_in[10];
  const float* Wcls = (const float*)d_in[11];
  const float* bcls = (const float*)d_in[12];
  float* out = (float*)d_out;

  char* ws = (char*)d_ws;
  u16* enhb   = (u16*)(ws);                    // 35,651,584  [8192][2176]
  u16* bufF   = (u16*)(ws + 35651584);         // 33,554,432  Wt_in+xb -> expw/h1/h3
  u16* bufA   = (u16*)(ws + 69206016);         //  8,912,896  Wt_e -> Wt_cls
  u16* Wt_o   = (u16*)(ws + 78118912);         //    524,288  [2048][128]
  u16* bufW1  = (u16*)(ws + 78643200);         //  8,388,608  Wh0 -> Wh2
  u16* bufW2  = (u16*)(ws + 87031808);         //  8,388,608  Wh1
  u16* comb   = (u16*)(ws + 95420416);         //  2,097,152  [8192][128]
  float* partials = (float*)(ws + 97517568);   //  1,048,576
  float* gate     = (float*)(ws + 98566144);   //    524,288
  u16* Wt_in  = bufF;                          // [2048][1024], dead after proj
  u16* xb     = bufF + 2097152;                // [8192][1024] bf16, dead after proj
  u16* Wt_e   = bufA;                          // [2048][2176], dead after expert
  u16* Wt_cls = bufA;                          // [1024][2048]

  hipFuncSetAttribute((const void*)gemm8<EP_PROJ>,
                      hipFuncAttributeMaxDynamicSharedMemorySize, 131072);
  hipFuncSetAttribute((const void*)gemm8<EP_EXPERT>,
                      hipFuncAttributeMaxDynamicSharedMemorySize, 131072);
  hipFuncSetAttribute((const void*)gemm8<EP_CTX>,
                      hipFuncAttributeMaxDynamicSharedMemorySize, 131072);
  hipFuncSetAttribute((const void*)gemm8<EP_RELU>,
                      hipFuncAttributeMaxDynamicSharedMemorySize, 131072);
  hipFuncSetAttribute((const void*)gemm8<EP_OUT>,
                      hipFuncAttributeMaxDynamicSharedMemorySize, 131072);

  // ---- conversions needed before the first GEMMs
  f32_to_bf16_k<<<4096, 256, 0, stream>>>(x, xb);
  transpose_conv_k<<<dim3(32, 16, 1), 256, 0, stream>>>(W_in, Wt_in, 1024, 2048, 1024, 0, 0);
  transpose_conv_k<<<dim3(2, 34, 16), 256, 0, stream>>>(We, Wt_e, 2176, 128, 2176, 2176L * 128L, 128);
  transpose_conv_k<<<dim3(32, 2, 1), 256, 0, stream>>>(Wo, Wt_o, 128, 2048, 128, 0, 0);
  transpose_conv_k<<<dim3(32, 32, 1), 256, 0, stream>>>(Wh, bufW1, 2048, 2048, 2048, 0, 0);
  transpose_conv_k<<<dim3(32, 32, 1), 256, 0, stream>>>(Wh + 2048L * 2048L, bufW2, 2048, 2048, 2048, 0, 0);

  // 1) proj = x @ W_in + b_in -> enhb[:, :2048] + row partial sums
  gemm8<EP_PROJ><<<dim3(8, 32), 512, 131072, stream>>>(
      xb, Wt_in, b_in, (void*)enhb, nullptr, partials, 1024, 1024, 1024, 2176, 2048);
  // 2) phasor bank -> enhb[:, 2048:]
  temporal_k<<<8192, 128, 0, stream>>>(partials, enhb);
  // 3) softmax gate
  gate_k<<<512, 256, 0, stream>>>(enhb, Wg, bg, gate);
  // 4) experts: relu(enh @ We + be) * gate
  gemm8<EP_EXPERT><<<dim3(8, 32), 512, 131072, stream>>>(
      enhb, Wt_e, be, (void*)bufF, gate, nullptr, 2176, 2176, 2176, 2048, 2048);
  // Wt_e dead -> convert Wcls into bufA
  transpose_conv_k<<<dim3(16, 32, 1), 256, 0, stream>>>(Wcls, Wt_cls, 2048, 1000, 2048, 0, 0);
  // 5) combine experts
  combine_k<<<4096, 256, 0, stream>>>(bufF, comb);
  // 6) context = comb @ Wo + bo, cols<20 doubled -> attended (enhb region)
  gemm8<EP_CTX><<<dim3(8, 32), 512, 131072, stream>>>(
      comb, Wt_o, bo, (void*)enhb, nullptr, nullptr, 128, 128, 128, 2048, 2048);
  // 7) MLP: h1 -> bufF, h2 -> enhb, h3 -> bufF
  gemm8<EP_RELU><<<dim3(8, 32), 512, 131072, stream>>>(
      enhb, bufW1, bh, (void*)bufF, nullptr, nullptr, 2048, 2048, 2048, 2048, 2048);
  transpose_conv_k<<<dim3(32, 32, 1), 256, 0, stream>>>(Wh + 2L * 2048L * 2048L, bufW1, 2048, 2048, 2048, 0, 0);
  gemm8<EP_RELU><<<dim3(8, 32), 512, 131072, stream>>>(
      bufF, bufW2, bh + 2048, (void*)enhb, nullptr, nullptr, 2048, 2048, 2048, 2048, 2048);
  gemm8<EP_RELU><<<dim3(8, 32), 512, 131072, stream>>>(
      enhb, bufW1, bh + 4096, (void*)bufF, nullptr, nullptr, 2048, 2048, 2048, 2048, 2048);
  // 8) logits (N=1000 -> padded 1024; Wt_cls rows >=1000 are zero; stores masked)
  gemm8<EP_OUT><<<dim3(4, 32), 512, 131072, stream>>>(
      bufF, Wt_cls, bcls, (void*)out, nullptr, nullptr, 2048, 2048, 2048, 1000, 1000);
}

// Round 4
// 438.350 us; speedup vs baseline: 3.5047x; 1.0259x over previous
//
#include <hip/hip_runtime.h>
#include <math.h>

// ---------------------------------------------------------------------------
// SophisticatedBioInspiredModel — bf16 MFMA, 256^2 8-phase GEMMs (gfx950).
//
// Spiking attention is data-independent: 100 distinct tokens, each bumped once
// from decayed-zero -> v=1.0 < 1.2 -> no spikes -> counts==0 -> top_k(zeros,20)
// = indices 0..19 -> gains double cols 0..19 of context.
//
// GEMM: C = A(MxK,bf16) * Bt(NxK,bf16)^T. 256x256 tile, BK=64, 8 waves (2Mx4N),
// 128 KiB LDS double-buffer, 8-phase schedule, counted vmcnt(4) (never 0 in
// main loop), chunk^(row&7) swizzle (0 bank conflicts, verified), setprio,
// bijective XCD swizzle. Epilogue: per-wave LDS restage -> dwordx4 stores.
// ---------------------------------------------------------------------------

typedef unsigned short u16;
typedef __attribute__((ext_vector_type(8))) short bfrag8;
typedef __attribute__((ext_vector_type(4))) float facc4;

__device__ __forceinline__ u16 f2bf(float f) {
  union { float f; unsigned u; } c; c.f = f;
  unsigned u = c.u;
  return (u16)((u + 0x7fffu + ((u >> 16) & 1u)) >> 16);
}
__device__ __forceinline__ float bf2f(u16 h) {
  union { unsigned u; float f; } c; c.u = ((unsigned)h) << 16;
  return c.f;
}
__device__ __forceinline__ void gload16(const void* g, void* lds) {
  __builtin_amdgcn_global_load_lds(
      (const __attribute__((address_space(1))) unsigned*)g,
      (__attribute__((address_space(3))) unsigned*)lds, 16, 0, 0);
}

#define BARX() do { __builtin_amdgcn_sched_barrier(0); \
  __builtin_amdgcn_s_barrier(); __builtin_amdgcn_sched_barrier(0); } while (0)
#define LGKM0() do { asm volatile("s_waitcnt lgkmcnt(0)" ::: "memory"); \
  __builtin_amdgcn_sched_barrier(0); } while (0)
#define VMW4() do { asm volatile("s_waitcnt vmcnt(4)" ::: "memory"); \
  __builtin_amdgcn_sched_barrier(0); } while (0)

#define RDA_(dst, mbase, dbuf) do { \
  char* _b = smem + (dbuf) * 65536; \
  _Pragma("unroll") for (int mm = 0; mm < 4; ++mm) { \
    int _row = wr * 128 + ((mbase) + mm) * 16 + r15; \
    _Pragma("unroll") for (int ks = 0; ks < 2; ++ks) \
      dst[mm][ks] = *(const bfrag8*)(_b + _row * 128 + \
                                     (((g + ks * 4) ^ (_row & 7)) << 4)); \
  } } while (0)

#define RDB_(dst, nbase, dbuf) do { \
  char* _b = smem + (dbuf) * 65536 + 32768; \
  _Pragma("unroll") for (int nn = 0; nn < 2; ++nn) { \
    int _row = wc * 64 + ((nbase) + nn) * 16 + r15; \
    _Pragma("unroll") for (int ks = 0; ks < 2; ++ks) \
      dst[nn][ks] = *(const bfrag8*)(_b + _row * 128 + \
                                     (((g + ks * 4) ^ (_row & 7)) << 4)); \
  } } while (0)

#define MF_(a, b, mo, no) do { \
  __builtin_amdgcn_s_setprio(1); \
  _Pragma("unroll") for (int mm = 0; mm < 4; ++mm) \
  _Pragma("unroll") for (int nn = 0; nn < 2; ++nn) \
  _Pragma("unroll") for (int ks = 0; ks < 2; ++ks) \
    acc[(mo) + mm][(no) + nn] = __builtin_amdgcn_mfma_f32_16x16x32_bf16( \
        a[mm][ks], b[nn][ks], acc[(mo) + mm][(no) + nn], 0, 0, 0); \
  __builtin_amdgcn_s_setprio(0); \
} while (0)

enum { EP_PROJ = 0, EP_EXPERT = 1, EP_CTX = 2, EP_RELU = 3, EP_OUT = 4 };

// Grid: (N/256, M/256). K%64==0, K/64 even and >=2. A rows %256==0, Bt rows %256==0.
template<int EP>
__global__ __launch_bounds__(512, 2)
void gemm8(const u16* __restrict__ A, const u16* __restrict__ Bt,
           const float* __restrict__ bias, void* __restrict__ Cp,
           const float* __restrict__ gate, float* __restrict__ partials,
           int K, int lda, int ldb, int ldc, int nvalid)
{
  extern __shared__ char smem[];   // 131072 B: [dbuf][A 32K | B 32K]
  const int t = threadIdx.x;
  const int lane = t & 63, wid = t >> 6;
  const int wr = wid >> 2, wc = wid & 3;
  const int g = lane >> 4, r15 = lane & 15;

  // bijective XCD swizzle (nblk % 8 == 0 for all our grids)
  const int nblk = gridDim.x * gridDim.y;
  const int flat = blockIdx.y * gridDim.x + blockIdx.x;
  const int swz = (flat & 7) * (nblk >> 3) + (flat >> 3);
  const int bx = swz % gridDim.x, by = swz / gridDim.x;

  const long a0 = (long)(by * 256) * lda;
  const long b0 = (long)(bx * 256) * ldb;

  facc4 acc[8][4];
#pragma unroll
  for (int m = 0; m < 8; m++)
#pragma unroll
    for (int n = 0; n < 4; n++) acc[m][n] = (facc4){0.f, 0.f, 0.f, 0.f};

  const int r0 = t >> 3, c0s = t & 7;
  const int csw = ((c0s ^ (r0 & 7)) << 3);   // swizzled k-chunk (elems)

  // which: 0=A-half0, 1=A-half1, 2=B-half0, 3=B-half1
  auto STAGE = [&](int kt, int which, int dbuf) {
    const int half = which & 1;
    const u16* gsrc;
    int ld;
    char* ldst = smem + dbuf * 65536 + half * 16384;
    if (which < 2) { gsrc = A + a0; ld = lda; }
    else           { gsrc = Bt + b0; ld = ldb; ldst += 32768; }
    gsrc += (long)(half * 128 + r0) * ld + kt * 64 + csw;
    gload16(gsrc, ldst + (t << 4));
    gload16(gsrc + 64L * ld, ldst + ((512 + t) << 4));
  };

  const int NT = K >> 6;
  STAGE(0, 0, 0); STAGE(0, 1, 0); STAGE(0, 2, 0); STAGE(0, 3, 0);
  STAGE(1, 0, 1); STAGE(1, 1, 1);
  VMW4(); BARX();

  bfrag8 aE[4][2], aO[4][2], b01[2][2], b23[2][2];

  for (int it = 0; it < (NT >> 1); ++it) {
    const int T = 2 * it;
    const int tp1 = T + 1;
    const int tp2 = (T + 2 < NT) ? T + 2 : NT - 1;
    const int tp3 = (T + 3 < NT) ? T + 3 : NT - 1;
    // p1
    RDA_(aE, 0, 0); RDB_(b01, 0, 0); STAGE(tp1, 2, 1);
    BARX(); LGKM0(); MF_(aE, b01, 0, 0); BARX();
    // p2
    RDA_(aO, 4, 0); STAGE(tp1, 3, 1);
    BARX(); LGKM0(); MF_(aO, b01, 4, 0); BARX();
    // p3
    RDB_(b23, 2, 0); STAGE(tp2, 0, 0);
    BARX(); LGKM0(); MF_(aO, b23, 4, 2); BARX();
    // p4
    STAGE(tp2, 1, 0); VMW4();
    BARX(); MF_(aE, b23, 0, 2); BARX();
    // p5
    RDA_(aE, 0, 1); RDB_(b01, 0, 1); STAGE(tp2, 2, 0);
    BARX(); LGKM0(); MF_(aE, b01, 0, 0); BARX();
    // p6
    RDA_(aO, 4, 1); STAGE(tp2, 3, 0);
    BARX(); LGKM0(); MF_(aO, b01, 4, 0); BARX();
    // p7
    RDB_(b23, 2, 1); STAGE(tp3, 0, 1);
    BARX(); LGKM0(); MF_(aO, b23, 4, 2); BARX();
    // p8
    STAGE(tp3, 1, 1); VMW4();
    BARX(); MF_(aE, b23, 0, 2); BARX();
  }

  // ---- epilogue: drain prefetches (they alias slab space), then LDS restage.
  asm volatile("s_waitcnt vmcnt(0)" ::: "memory");
  __builtin_amdgcn_sched_barrier(0);
  __builtin_amdgcn_s_barrier();
  __builtin_amdgcn_sched_barrier(0);

  const int rbase = by * 256 + wr * 128;
  const int cbase = bx * 256 + wc * 64;
  float* slab = (float*)(smem + wid * 8704);   // per-wave [32][68] f32

  float psum[8][4];
  if (EP == EP_PROJ) {
#pragma unroll
    for (int m = 0; m < 8; m++)
#pragma unroll
      for (int r = 0; r < 4; r++) psum[m][r] = 0.f;
  }

#pragma unroll
  for (int pass = 0; pass < 4; ++pass) {
#pragma unroll
    for (int mm = 0; mm < 2; ++mm) {
      const int m = pass * 2 + mm;
#pragma unroll
      for (int n = 0; n < 4; ++n)
#pragma unroll
        for (int r = 0; r < 4; ++r) {
          const int rowp = mm * 16 + g * 4 + r;
          const int grow = rbase + m * 16 + g * 4 + r;
          const int gcol = cbase + n * 16 + r15;
          float val = acc[m][n][r] + bias[gcol];
          if (EP == EP_EXPERT)
            val = fmaxf(val, 0.f) * gate[(long)grow * 16 + (gcol >> 7)];
          if (EP == EP_CTX && gcol < 20) val *= 2.0f;   // spiking attention
          if (EP == EP_RELU) val = fmaxf(val, 0.f);
          if (EP == EP_PROJ) psum[m][r] += val;
          slab[rowp * 68 + n * 16 + r15] = val;
        }
    }
    // wave-private slab; DS ops in-order within a wave (compiler inserts waits)
#pragma unroll
    for (int rep = 0; rep < 4; ++rep) {
      const int rowp = rep * 8 + (lane >> 3);
      const int cc = (lane & 7) * 8;
      const facc4 v0 = *(const facc4*)&slab[rowp * 68 + cc];
      const facc4 v1 = *(const facc4*)&slab[rowp * 68 + cc + 4];
      const long grow = rbase + pass * 32 + rowp;
      const int gcol0 = cbase + cc;
      if (EP == EP_OUT) {
        float* Cf = (float*)Cp;
        if (gcol0 + 7 < nvalid) {
          *(facc4*)(Cf + grow * ldc + gcol0) = v0;
          *(facc4*)(Cf + grow * ldc + gcol0 + 4) = v1;
        } else {
#pragma unroll
          for (int j = 0; j < 4; ++j)
            if (gcol0 + j < nvalid) Cf[grow * ldc + gcol0 + j] = v0[j];
#pragma unroll
          for (int j = 0; j < 4; ++j)
            if (gcol0 + 4 + j < nvalid) Cf[grow * ldc + gcol0 + 4 + j] = v1[j];
        }
      } else {
        u16 o[8];
        o[0] = f2bf(v0[0]); o[1] = f2bf(v0[1]);
        o[2] = f2bf(v0[2]); o[3] = f2bf(v0[3]);
        o[4] = f2bf(v1[0]); o[5] = f2bf(v1[1]);
        o[6] = f2bf(v1[2]); o[7] = f2bf(v1[3]);
        *(uint4*)((u16*)Cp + grow * ldc + gcol0) = *(const uint4*)o;
      }
    }
  }

  if (EP == EP_PROJ) {
#pragma unroll
    for (int m = 0; m < 8; m++)
#pragma unroll
      for (int r = 0; r < 4; r++) {
        float p = psum[m][r];
        p += __shfl_xor(p, 1); p += __shfl_xor(p, 2);
        p += __shfl_xor(p, 4); p += __shfl_xor(p, 8);
        if (r15 == 0)
          partials[(long)(rbase + m * 16 + g * 4 + r) * 32 + bx * 4 + wc] = p;
      }
  }
}

// out[n][k] = bf16(in[k][n]); pads rows n>=N with zeros. Grid: (ceil(N/64), K/64, Z).
__global__ __launch_bounds__(256)
void transpose_conv_k(const float* __restrict__ in, u16* __restrict__ out,
                      int K, int N, int ldout, long in_zstride, int out_zrows)
{
  __shared__ float tile[64][65];
  const int t = threadIdx.x;
  const int n0 = blockIdx.x * 64, k0 = blockIdx.y * 64;
  const float* src = in + (long)blockIdx.z * in_zstride;
  const int rr = t >> 4;
  const int cc = (t & 15) * 4;
#pragma unroll
  for (int j = 0; j < 4; j++) {
    int k = k0 + j * 16 + rr;
    int n = n0 + cc;
    float v0 = 0.f, v1 = 0.f, v2 = 0.f, v3 = 0.f;
    if (n + 3 < N) {
      facc4 v = *(const facc4*)(src + (long)k * N + n);
      v0 = v[0]; v1 = v[1]; v2 = v[2]; v3 = v[3];
    } else {
      if (n < N)     v0 = src[(long)k * N + n];
      if (n + 1 < N) v1 = src[(long)k * N + n + 1];
      if (n + 2 < N) v2 = src[(long)k * N + n + 2];
      if (n + 3 < N) v3 = src[(long)k * N + n + 3];
    }
    float* trow = &tile[j * 16 + rr][cc];
    trow[0] = v0; trow[1] = v1; trow[2] = v2; trow[3] = v3;
  }
  __syncthreads();
  const int n_l = t >> 2;
  const int kc = (t & 3) * 16;
  const int n_gl = n0 + n_l;
  u16 o16[16];
  const bool valid = n_gl < N;
#pragma unroll
  for (int i = 0; i < 16; i++) o16[i] = valid ? f2bf(tile[kc + i][n_l]) : (u16)0;
  long orow = (long)blockIdx.z * out_zrows + n_gl;
  u16* dst = out + orow * (long)ldout + k0 + kc;
  *(uint4*)dst = ((const uint4*)o16)[0];
  *(uint4*)(dst + 8) = ((const uint4*)o16)[1];
}

__global__ __launch_bounds__(256)
void f32_to_bf16_k(const float* __restrict__ in, u16* __restrict__ out)
{
  const long i = ((long)blockIdx.x * 256 + threadIdx.x) * 8;
  facc4 v0 = *(const facc4*)(in + i);
  facc4 v1 = *(const facc4*)(in + i + 4);
  u16 o[8];
  o[0] = f2bf(v0[0]); o[1] = f2bf(v0[1]); o[2] = f2bf(v0[2]); o[3] = f2bf(v0[3]);
  o[4] = f2bf(v1[0]); o[5] = f2bf(v1[1]); o[6] = f2bf(v1[2]); o[7] = f2bf(v1[3]);
  *(uint4*)(out + i) = *(const uint4*)o;
}

__global__ __launch_bounds__(128)
void temporal_k(const float* __restrict__ partials, u16* __restrict__ enh)
{
  __shared__ float tsh;
  const int b = blockIdx.x;
  const int j = threadIdx.x;  // 128
  if (j < 32) {
    float p = partials[(long)b * 32 + j];
    p += __shfl_xor(p, 1); p += __shfl_xor(p, 2); p += __shfl_xor(p, 4);
    p += __shfl_xor(p, 8); p += __shfl_xor(p, 16);
    if (j == 0) tsh = p;
  }
  __syncthreads();
  float tmean = tsh * (1.0f / 2048.0f);
  float v;
  if (j < 64) v = sinf(7.0f * tmean * (float)(j + 1));
  else        v = cosf(7.0f * tmean * (float)(j - 63));
  enh[(long)b * 2176 + 2048 + j] = f2bf(v);
}

// gate = softmax(enh @ Wg + bg); 8 rows/block staged in LDS once.
__global__ __launch_bounds__(128)
void gate_k(const u16* __restrict__ enh, const float* __restrict__ Wg,
            const float* __restrict__ bg, float* __restrict__ gate)
{
  __shared__ u16 lds[8][2184];   // +8 pad: row stride 1092 words, banks spread
  const int t = threadIdx.x;
  const long row0 = (long)blockIdx.x * 8;
#pragma unroll
  for (int r8 = 0; r8 < 8; ++r8) {
    const u16* src = enh + (row0 + r8) * 2176;
    u16* dst = &lds[r8][0];
    *(uint4*)(dst + t * 8) = *(const uint4*)(src + t * 8);
    *(uint4*)(dst + (128 + t) * 8) = *(const uint4*)(src + (128 + t) * 8);
    if (t < 16)
      *(uint4*)(dst + (256 + t) * 8) = *(const uint4*)(src + (256 + t) * 8);
  }
  __syncthreads();
  const int r = t >> 4, e = t & 15;
  float acc = bg[e];
  for (int k = 0; k < 2176; k += 8) {
    uint4 a = *(const uint4*)&lds[r][k];
    const u16* ap = (const u16*)&a;
#pragma unroll
    for (int j = 0; j < 8; ++j)
      acc += bf2f(ap[j]) * Wg[(k + j) * 16 + e];
  }
  float mx = acc;
  mx = fmaxf(mx, __shfl_xor(mx, 8)); mx = fmaxf(mx, __shfl_xor(mx, 4));
  mx = fmaxf(mx, __shfl_xor(mx, 2)); mx = fmaxf(mx, __shfl_xor(mx, 1));
  float ex = expf(acc - mx);
  float sum = ex;
  sum += __shfl_xor(sum, 8); sum += __shfl_xor(sum, 4);
  sum += __shfl_xor(sum, 2); sum += __shfl_xor(sum, 1);
  gate[(row0 + r) * 16 + e] = ex / sum;
}

// comb[b][k] = sum_e expw[b][e*128+k], 8 k's per thread
__global__ __launch_bounds__(256)
void combine_k(const u16* __restrict__ expw, u16* __restrict__ comb)
{
  const long i = ((long)blockIdx.x * 256 + threadIdx.x) * 8;
  const long b = i >> 7;
  const int k = (int)(i & 127);
  float s[8] = {0.f, 0.f, 0.f, 0.f, 0.f, 0.f, 0.f, 0.f};
#pragma unroll
  for (int e = 0; e < 16; ++e) {
    uint4 v = *(const uint4*)(expw + b * 2048 + e * 128 + k);
    const u16* vp = (const u16*)&v;
#pragma unroll
    for (int j = 0; j < 8; ++j) s[j] += bf2f(vp[j]);
  }
  u16 o[8];
#pragma unroll
  for (int j = 0; j < 8; ++j) o[j] = f2bf(s[j]);
  *(uint4*)(comb + i) = *(const uint4*)o;
}

extern "C" void kernel_launch(void* const* d_in, const int* in_sizes, int n_in,
                              void* d_out, int out_size, void* d_ws,
                              size_t ws_size, hipStream_t stream)
{
  const float* x    = (const float*)d_in[0];
  const float* W_in = (const float*)d_in[1];
  const float* b_in = (const float*)d_in[2];
  const float* Wg   = (const float*)d_in[3];
  const float* bg   = (const float*)d_in[4];
  const float* We   = (const float*)d_in[5];
  const float* be   = (const float*)d_in[6];
  const float* Wo   = (const float*)d_in[7];
  const float* bo   = (const float*)d_in[8];
  const float* Wh   = (const float*)d_in[9];
  const float* bh   = (const float*)d_in[10];
  const float* Wcls = (const float*)d_in[11];
  const float* bcls = (const float*)d_in[12];
  float* out = (float*)d_out;

  char* ws = (char*)d_ws;
  u16* enhb   = (u16*)(ws);                    // 35,651,584  [8192][2176]
  u16* bufF   = (u16*)(ws + 35651584);         // 33,554,432  Wt_in+xb -> expw/h1/h3
  u16* bufA   = (u16*)(ws + 69206016);         //  8,912,896  Wt_e -> Wt_cls
  u16* Wt_o   = (u16*)(ws + 78118912);         //    524,288  [2048][128]
  u16* bufW1  = (u16*)(ws + 78643200);         //  8,388,608  Wh0 -> Wh2
  u16* bufW2  = (u16*)(ws + 87031808);         //  8,388,608  Wh1
  u16* comb   = (u16*)(ws + 95420416);         //  2,097,152  [8192][128]
  float* partials = (float*)(ws + 97517568);   //  1,048,576
  float* gate     = (float*)(ws + 98566144);   //    524,288
  u16* Wt_in  = bufF;                          // [2048][1024], dead after proj
  u16* xb     = bufF + 2097152;                // [8192][1024] bf16, dead after proj
  u16* Wt_e   = bufA;                          // [2048][2176], dead after expert
  u16* Wt_cls = bufA;                          // [1024][2048]

  hipFuncSetAttribute((const void*)gemm8<EP_PROJ>,
                      hipFuncAttributeMaxDynamicSharedMemorySize, 131072);
  hipFuncSetAttribute((const void*)gemm8<EP_EXPERT>,
                      hipFuncAttributeMaxDynamicSharedMemorySize, 131072);
  hipFuncSetAttribute((const void*)gemm8<EP_CTX>,
                      hipFuncAttributeMaxDynamicSharedMemorySize, 131072);
  hipFuncSetAttribute((const void*)gemm8<EP_RELU>,
                      hipFuncAttributeMaxDynamicSharedMemorySize, 131072);
  hipFuncSetAttribute((const void*)gemm8<EP_OUT>,
                      hipFuncAttributeMaxDynamicSharedMemorySize, 131072);

  // ---- conversions needed before the first GEMMs
  f32_to_bf16_k<<<4096, 256, 0, stream>>>(x, xb);
  transpose_conv_k<<<dim3(32, 16, 1), 256, 0, stream>>>(W_in, Wt_in, 1024, 2048, 1024, 0, 0);
  transpose_conv_k<<<dim3(2, 34, 16), 256, 0, stream>>>(We, Wt_e, 2176, 128, 2176, 2176L * 128L, 128);
  transpose_conv_k<<<dim3(32, 2, 1), 256, 0, stream>>>(Wo, Wt_o, 128, 2048, 128, 0, 0);
  // Wh0 -> bufW1, Wh1 -> bufW2 (contiguous): one z=2 launch
  transpose_conv_k<<<dim3(32, 32, 2), 256, 0, stream>>>(Wh, bufW1, 2048, 2048, 2048, 2048L * 2048L, 2048);

  // 1) proj = x @ W_in + b_in -> enhb[:, :2048] + row partial sums
  gemm8<EP_PROJ><<<dim3(8, 32), 512, 131072, stream>>>(
      xb, Wt_in, b_in, (void*)enhb, nullptr, partials, 1024, 1024, 1024, 2176, 2048);
  // 2) phasor bank -> enhb[:, 2048:]
  temporal_k<<<8192, 128, 0, stream>>>(partials, enhb);
  // 3) softmax gate
  gate_k<<<1024, 128, 0, stream>>>(enhb, Wg, bg, gate);
  // 4) experts: relu(enh @ We + be) * gate
  gemm8<EP_EXPERT><<<dim3(8, 32), 512, 131072, stream>>>(
      enhb, Wt_e, be, (void*)bufF, gate, nullptr, 2176, 2176, 2176, 2048, 2048);
  // Wt_e dead -> convert Wcls into bufA
  transpose_conv_k<<<dim3(16, 32, 1), 256, 0, stream>>>(Wcls, Wt_cls, 2048, 1000, 2048, 0, 0);
  // 5) combine experts
  combine_k<<<512, 256, 0, stream>>>(bufF, comb);
  // 6) context = comb @ Wo + bo, cols<20 doubled -> attended (enhb region)
  gemm8<EP_CTX><<<dim3(8, 32), 512, 131072, stream>>>(
      comb, Wt_o, bo, (void*)enhb, nullptr, nullptr, 128, 128, 128, 2048, 2048);
  // 7) MLP: h1 -> bufF, h2 -> enhb, h3 -> bufF
  gemm8<EP_RELU><<<dim3(8, 32), 512, 131072, stream>>>(
      enhb, bufW1, bh, (void*)bufF, nullptr, nullptr, 2048, 2048, 2048, 2048, 2048);
  transpose_conv_k<<<dim3(32, 32, 1), 256, 0, stream>>>(Wh + 2L * 2048L * 2048L, bufW1, 2048, 2048, 2048, 0, 0);
  gemm8<EP_RELU><<<dim3(8, 32), 512, 131072, stream>>>(
      bufF, bufW2, bh + 2048, (void*)enhb, nullptr, nullptr, 2048, 2048, 2048, 2048, 2048);
  gemm8<EP_RELU><<<dim3(8, 32), 512, 131072, stream>>>(
      enhb, bufW1, bh + 4096, (void*)bufF, nullptr, nullptr, 2048, 2048, 2048, 2048, 2048);
  // 8) logits (N=1000 -> padded 1024; Wt_cls rows >=1000 are zero; stores masked)
  gemm8<EP_OUT><<<dim3(4, 32), 512, 131072, stream>>>(
      bufF, Wt_cls, bcls, (void*)out, nullptr, nullptr, 2048, 2048, 2048, 1000, 1000);
}

// Round 5
// 427.021 us; speedup vs baseline: 3.5977x; 1.0265x over previous
//
#include <hip/hip_runtime.h>
#include <math.h>

// ---------------------------------------------------------------------------
// SophisticatedBioInspiredModel — bf16 MFMA, 256^2 6-phase GEMMs (gfx950).
//
// Spiking attention is data-independent: 100 distinct tokens, each bumped once
// from decayed-zero -> v=1.0 < 1.2 -> no spikes -> counts==0 -> top_k(zeros,20)
// = indices 0..19 -> gains double cols 0..19 of context.
//
// GEMM: C = A(MxK,bf16) * Bt(NxK,bf16)^T. 256x256 tile, BK=64, 8 waves (2Mx4N),
// 128 KiB LDS double-buffer. 6-phase schedule per 2 K-tiles: each phase is
// {ds_reads ; stage ; lgkmcnt(0) ; MFMA ; barrier} — NO barrier between reads
// and MFMA (hazards carried by end-of-phase barriers + per-wave lgkmcnt +
// counted vmcnt(4) at P3/P6, placed AFTER the MFMA cluster). chunk^(row&7)
// swizzle (0 conflicts), setprio, bijective XCD swizzle, LDS-restaged stores.
// ---------------------------------------------------------------------------

typedef unsigned short u16;
typedef __attribute__((ext_vector_type(8))) short bfrag8;
typedef __attribute__((ext_vector_type(4))) float facc4;

__device__ __forceinline__ u16 f2bf(float f) {
  union { float f; unsigned u; } c; c.f = f;
  unsigned u = c.u;
  return (u16)((u + 0x7fffu + ((u >> 16) & 1u)) >> 16);
}
__device__ __forceinline__ float bf2f(u16 h) {
  union { unsigned u; float f; } c; c.u = ((unsigned)h) << 16;
  return c.f;
}
__device__ __forceinline__ void gload16(const void* g, void* lds) {
  __builtin_amdgcn_global_load_lds(
      (const __attribute__((address_space(1))) unsigned*)g,
      (__attribute__((address_space(3))) unsigned*)lds, 16, 0, 0);
}

#define BARX() do { __builtin_amdgcn_sched_barrier(0); \
  __builtin_amdgcn_s_barrier(); __builtin_amdgcn_sched_barrier(0); } while (0)
#define LGKM0() do { asm volatile("s_waitcnt lgkmcnt(0)" ::: "memory"); \
  __builtin_amdgcn_sched_barrier(0); } while (0)
#define VMW4() do { asm volatile("s_waitcnt vmcnt(4)" ::: "memory"); \
  __builtin_amdgcn_sched_barrier(0); } while (0)

#define RDA_(dst, mbase, dbuf) do { \
  char* _b = smem + (dbuf) * 65536; \
  _Pragma("unroll") for (int mm = 0; mm < 4; ++mm) { \
    int _row = wr * 128 + ((mbase) + mm) * 16 + r15; \
    _Pragma("unroll") for (int ks = 0; ks < 2; ++ks) \
      dst[mm][ks] = *(const bfrag8*)(_b + _row * 128 + \
                                     (((g + ks * 4) ^ (_row & 7)) << 4)); \
  } } while (0)

#define RDB_(dst, nbase, dbuf) do { \
  char* _b = smem + (dbuf) * 65536 + 32768; \
  _Pragma("unroll") for (int nn = 0; nn < 2; ++nn) { \
    int _row = wc * 64 + ((nbase) + nn) * 16 + r15; \
    _Pragma("unroll") for (int ks = 0; ks < 2; ++ks) \
      dst[nn][ks] = *(const bfrag8*)(_b + _row * 128 + \
                                     (((g + ks * 4) ^ (_row & 7)) << 4)); \
  } } while (0)

#define MF_(a, b, mo, no) do { \
  __builtin_amdgcn_s_setprio(1); \
  _Pragma("unroll") for (int mm = 0; mm < 4; ++mm) \
  _Pragma("unroll") for (int nn = 0; nn < 2; ++nn) \
  _Pragma("unroll") for (int ks = 0; ks < 2; ++ks) \
    acc[(mo) + mm][(no) + nn] = __builtin_amdgcn_mfma_f32_16x16x32_bf16( \
        a[mm][ks], b[nn][ks], acc[(mo) + mm][(no) + nn], 0, 0, 0); \
  __builtin_amdgcn_s_setprio(0); \
} while (0)

enum { EP_PROJ = 0, EP_EXPERT = 1, EP_CTX = 2, EP_RELU = 3, EP_OUT = 4 };

// Grid: (N/256, M/256). K%64==0, K/64 even and >=2. A rows %256==0, Bt rows %256==0.
template<int EP>
__global__ __launch_bounds__(512, 2)
void gemm8(const u16* __restrict__ A, const u16* __restrict__ Bt,
           const float* __restrict__ bias, void* __restrict__ Cp,
           const float* __restrict__ gate, float* __restrict__ partials,
           int K, int lda, int ldb, int ldc, int nvalid)
{
  extern __shared__ char smem[];   // 131072 B: [dbuf][A 32K | B 32K]
  const int t = threadIdx.x;
  const int lane = t & 63, wid = t >> 6;
  const int wr = wid >> 2, wc = wid & 3;
  const int g = lane >> 4, r15 = lane & 15;

  // bijective XCD swizzle (nblk % 8 == 0 for all our grids)
  const int nblk = gridDim.x * gridDim.y;
  const int flat = blockIdx.y * gridDim.x + blockIdx.x;
  const int swz = (flat & 7) * (nblk >> 3) + (flat >> 3);
  const int bx = swz % gridDim.x, by = swz / gridDim.x;

  const long a0 = (long)(by * 256) * lda;
  const long b0 = (long)(bx * 256) * ldb;

  facc4 acc[8][4];
#pragma unroll
  for (int m = 0; m < 8; m++)
#pragma unroll
    for (int n = 0; n < 4; n++) acc[m][n] = (facc4){0.f, 0.f, 0.f, 0.f};

  const int r0 = t >> 3, c0s = t & 7;
  const int csw = ((c0s ^ (r0 & 7)) << 3);   // swizzled k-chunk (elems)

  // which: 0=A-half0, 1=A-half1, 2=B-half0, 3=B-half1
  auto STAGE = [&](int kt, int which, int dbuf) {
    const int half = which & 1;
    const u16* gsrc;
    int ld;
    char* ldst = smem + dbuf * 65536 + half * 16384;
    if (which < 2) { gsrc = A + a0; ld = lda; }
    else           { gsrc = Bt + b0; ld = ldb; ldst += 32768; }
    gsrc += (long)(half * 128 + r0) * ld + kt * 64 + csw;
    gload16(gsrc, ldst + (t << 4));
    gload16(gsrc + 64L * ld, ldst + ((512 + t) << 4));
  };

  const int NT = K >> 6;
  STAGE(0, 0, 0); STAGE(0, 1, 0); STAGE(0, 2, 0); STAGE(0, 3, 0);
  STAGE(1, 0, 1); STAGE(1, 1, 1);
  VMW4(); BARX();

  bfrag8 aE[4][2], aO[4][2], b01[2][2], b23[2][2];

  for (int it = 0; it < (NT >> 1); ++it) {
    const int T = 2 * it;
    const int tp1 = T + 1;
    const int tp2 = (T + 2 < NT) ? T + 2 : NT - 1;
    const int tp3 = (T + 3 < NT) ? T + 3 : NT - 1;
    // P1: read (aE,b01) from buf0(T); stage (T+1).B0 -> buf1
    RDA_(aE, 0, 0); RDB_(b01, 0, 0); STAGE(tp1, 2, 1);
    LGKM0(); MF_(aE, b01, 0, 0); BARX();
    // P2: read aO; stage (T+1).B1
    RDA_(aO, 4, 0); STAGE(tp1, 3, 1);
    LGKM0(); MF_(aO, b01, 4, 0); BARX();
    // P3: read b23; stage (T+2).A -> buf0; 32 MFMA; drain so buf1(T+1) ready
    RDB_(b23, 2, 0); STAGE(tp2, 0, 0); STAGE(tp2, 1, 0);
    LGKM0(); MF_(aO, b23, 4, 2); MF_(aE, b23, 0, 2);
    VMW4(); BARX();
    // P4: read (aE,b01) from buf1(T+1); stage (T+2).B0 -> buf0
    RDA_(aE, 0, 1); RDB_(b01, 0, 1); STAGE(tp2, 2, 0);
    LGKM0(); MF_(aE, b01, 0, 0); BARX();
    // P5: read aO; stage (T+2).B1
    RDA_(aO, 4, 1); STAGE(tp2, 3, 0);
    LGKM0(); MF_(aO, b01, 4, 0); BARX();
    // P6: read b23; stage (T+3).A -> buf1; 32 MFMA; drain so buf0(T+2) ready
    RDB_(b23, 2, 1); STAGE(tp3, 0, 1); STAGE(tp3, 1, 1);
    LGKM0(); MF_(aO, b23, 4, 2); MF_(aE, b23, 0, 2);
    VMW4(); BARX();
  }

  // ---- epilogue: drain prefetches (they alias slab space), then LDS restage.
  asm volatile("s_waitcnt vmcnt(0)" ::: "memory");
  __builtin_amdgcn_sched_barrier(0);
  __builtin_amdgcn_s_barrier();
  __builtin_amdgcn_sched_barrier(0);

  const int rbase = by * 256 + wr * 128;
  const int cbase = bx * 256 + wc * 64;
  float* slab = (float*)(smem + wid * 8704);   // per-wave [32][68] f32

  float psum[8][4];
  if (EP == EP_PROJ) {
#pragma unroll
    for (int m = 0; m < 8; m++)
#pragma unroll
      for (int r = 0; r < 4; r++) psum[m][r] = 0.f;
  }

#pragma unroll
  for (int pass = 0; pass < 4; ++pass) {
#pragma unroll
    for (int mm = 0; mm < 2; ++mm) {
      const int m = pass * 2 + mm;
#pragma unroll
      for (int n = 0; n < 4; ++n)
#pragma unroll
        for (int r = 0; r < 4; ++r) {
          const int rowp = mm * 16 + g * 4 + r;
          const int grow = rbase + m * 16 + g * 4 + r;
          const int gcol = cbase + n * 16 + r15;
          float val = acc[m][n][r] + bias[gcol];
          if (EP == EP_EXPERT)
            val = fmaxf(val, 0.f) * gate[(long)grow * 16 + (gcol >> 7)];
          if (EP == EP_CTX && gcol < 20) val *= 2.0f;   // spiking attention
          if (EP == EP_RELU) val = fmaxf(val, 0.f);
          if (EP == EP_PROJ) psum[m][r] += val;
          slab[rowp * 68 + n * 16 + r15] = val;
        }
    }
    // wave-private slab; DS ops in-order within a wave (compiler inserts waits)
#pragma unroll
    for (int rep = 0; rep < 4; ++rep) {
      const int rowp = rep * 8 + (lane >> 3);
      const int cc = (lane & 7) * 8;
      const facc4 v0 = *(const facc4*)&slab[rowp * 68 + cc];
      const facc4 v1 = *(const facc4*)&slab[rowp * 68 + cc + 4];
      const long grow = rbase + pass * 32 + rowp;
      const int gcol0 = cbase + cc;
      if (EP == EP_OUT) {
        float* Cf = (float*)Cp;
        if (gcol0 + 7 < nvalid) {
          *(facc4*)(Cf + grow * ldc + gcol0) = v0;
          *(facc4*)(Cf + grow * ldc + gcol0 + 4) = v1;
        } else {
#pragma unroll
          for (int j = 0; j < 4; ++j)
            if (gcol0 + j < nvalid) Cf[grow * ldc + gcol0 + j] = v0[j];
#pragma unroll
          for (int j = 0; j < 4; ++j)
            if (gcol0 + 4 + j < nvalid) Cf[grow * ldc + gcol0 + 4 + j] = v1[j];
        }
      } else {
        u16 o[8];
        o[0] = f2bf(v0[0]); o[1] = f2bf(v0[1]);
        o[2] = f2bf(v0[2]); o[3] = f2bf(v0[3]);
        o[4] = f2bf(v1[0]); o[5] = f2bf(v1[1]);
        o[6] = f2bf(v1[2]); o[7] = f2bf(v1[3]);
        *(uint4*)((u16*)Cp + grow * ldc + gcol0) = *(const uint4*)o;
      }
    }
  }

  if (EP == EP_PROJ) {
#pragma unroll
    for (int m = 0; m < 8; m++)
#pragma unroll
      for (int r = 0; r < 4; r++) {
        float p = psum[m][r];
        p += __shfl_xor(p, 1); p += __shfl_xor(p, 2);
        p += __shfl_xor(p, 4); p += __shfl_xor(p, 8);
        if (r15 == 0)
          partials[(long)(rbase + m * 16 + g * 4 + r) * 32 + bx * 4 + wc] = p;
      }
  }
}

// out[n][k] = bf16(in[k][n]); pads rows n>=N with zeros. Grid: (ceil(N/64), K/64, Z).
__global__ __launch_bounds__(256)
void transpose_conv_k(const float* __restrict__ in, u16* __restrict__ out,
                      int K, int N, int ldout, long in_zstride, int out_zrows)
{
  __shared__ float tile[64][65];
  const int t = threadIdx.x;
  const int n0 = blockIdx.x * 64, k0 = blockIdx.y * 64;
  const float* src = in + (long)blockIdx.z * in_zstride;
  const int rr = t >> 4;
  const int cc = (t & 15) * 4;
#pragma unroll
  for (int j = 0; j < 4; j++) {
    int k = k0 + j * 16 + rr;
    int n = n0 + cc;
    float v0 = 0.f, v1 = 0.f, v2 = 0.f, v3 = 0.f;
    if (n + 3 < N) {
      facc4 v = *(const facc4*)(src + (long)k * N + n);
      v0 = v[0]; v1 = v[1]; v2 = v[2]; v3 = v[3];
    } else {
      if (n < N)     v0 = src[(long)k * N + n];
      if (n + 1 < N) v1 = src[(long)k * N + n + 1];
      if (n + 2 < N) v2 = src[(long)k * N + n + 2];
      if (n + 3 < N) v3 = src[(long)k * N + n + 3];
    }
    float* trow = &tile[j * 16 + rr][cc];
    trow[0] = v0; trow[1] = v1; trow[2] = v2; trow[3] = v3;
  }
  __syncthreads();
  const int n_l = t >> 2;
  const int kc = (t & 3) * 16;
  const int n_gl = n0 + n_l;
  u16 o16[16];
  const bool valid = n_gl < N;
#pragma unroll
  for (int i = 0; i < 16; i++) o16[i] = valid ? f2bf(tile[kc + i][n_l]) : (u16)0;
  long orow = (long)blockIdx.z * out_zrows + n_gl;
  u16* dst = out + orow * (long)ldout + k0 + kc;
  *(uint4*)dst = ((const uint4*)o16)[0];
  *(uint4*)(dst + 8) = ((const uint4*)o16)[1];
}

__global__ __launch_bounds__(256)
void f32_to_bf16_k(const float* __restrict__ in, u16* __restrict__ out)
{
  const long i = ((long)blockIdx.x * 256 + threadIdx.x) * 8;
  facc4 v0 = *(const facc4*)(in + i);
  facc4 v1 = *(const facc4*)(in + i + 4);
  u16 o[8];
  o[0] = f2bf(v0[0]); o[1] = f2bf(v0[1]); o[2] = f2bf(v0[2]); o[3] = f2bf(v0[3]);
  o[4] = f2bf(v1[0]); o[5] = f2bf(v1[1]); o[6] = f2bf(v1[2]); o[7] = f2bf(v1[3]);
  *(uint4*)(out + i) = *(const uint4*)o;
}

__global__ __launch_bounds__(128)
void temporal_k(const float* __restrict__ partials, u16* __restrict__ enh)
{
  __shared__ float tsh;
  const int b = blockIdx.x;
  const int j = threadIdx.x;  // 128
  if (j < 32) {
    float p = partials[(long)b * 32 + j];
    p += __shfl_xor(p, 1); p += __shfl_xor(p, 2); p += __shfl_xor(p, 4);
    p += __shfl_xor(p, 8); p += __shfl_xor(p, 16);
    if (j == 0) tsh = p;
  }
  __syncthreads();
  float tmean = tsh * (1.0f / 2048.0f);
  float v;
  if (j < 64) v = sinf(7.0f * tmean * (float)(j + 1));
  else        v = cosf(7.0f * tmean * (float)(j - 63));
  enh[(long)b * 2176 + 2048 + j] = f2bf(v);
}

// gate = softmax(enh @ Wg + bg); 8 rows/block staged in LDS once.
__global__ __launch_bounds__(128)
void gate_k(const u16* __restrict__ enh, const float* __restrict__ Wg,
            const float* __restrict__ bg, float* __restrict__ gate)
{
  __shared__ u16 lds[8][2184];   // +8 pad: banks spread
  const int t = threadIdx.x;
  const long row0 = (long)blockIdx.x * 8;
#pragma unroll
  for (int r8 = 0; r8 < 8; ++r8) {
    const u16* src = enh + (row0 + r8) * 2176;
    u16* dst = &lds[r8][0];
    *(uint4*)(dst + t * 8) = *(const uint4*)(src + t * 8);
    *(uint4*)(dst + (128 + t) * 8) = *(const uint4*)(src + (128 + t) * 8);
    if (t < 16)
      *(uint4*)(dst + (256 + t) * 8) = *(const uint4*)(src + (256 + t) * 8);
  }
  __syncthreads();
  const int r = t >> 4, e = t & 15;
  float acc = bg[e];
  for (int k = 0; k < 2176; k += 8) {
    uint4 a = *(const uint4*)&lds[r][k];
    const u16* ap = (const u16*)&a;
#pragma unroll
    for (int j = 0; j < 8; ++j)
      acc += bf2f(ap[j]) * Wg[(k + j) * 16 + e];
  }
  float mx = acc;
  mx = fmaxf(mx, __shfl_xor(mx, 8)); mx = fmaxf(mx, __shfl_xor(mx, 4));
  mx = fmaxf(mx, __shfl_xor(mx, 2)); mx = fmaxf(mx, __shfl_xor(mx, 1));
  float ex = expf(acc - mx);
  float sum = ex;
  sum += __shfl_xor(sum, 8); sum += __shfl_xor(sum, 4);
  sum += __shfl_xor(sum, 2); sum += __shfl_xor(sum, 1);
  gate[(row0 + r) * 16 + e] = ex / sum;
}

// comb[b][k] = sum_e expw[b][e*128+k], 8 k's per thread
__global__ __launch_bounds__(256)
void combine_k(const u16* __restrict__ expw, u16* __restrict__ comb)
{
  const long i = ((long)blockIdx.x * 256 + threadIdx.x) * 8;
  const long b = i >> 7;
  const int k = (int)(i & 127);
  float s[8] = {0.f, 0.f, 0.f, 0.f, 0.f, 0.f, 0.f, 0.f};
#pragma unroll
  for (int e = 0; e < 16; ++e) {
    uint4 v = *(const uint4*)(expw + b * 2048 + e * 128 + k);
    const u16* vp = (const u16*)&v;
#pragma unroll
    for (int j = 0; j < 8; ++j) s[j] += bf2f(vp[j]);
  }
  u16 o[8];
#pragma unroll
  for (int j = 0; j < 8; ++j) o[j] = f2bf(s[j]);
  *(uint4*)(comb + i) = *(const uint4*)o;
}

extern "C" void kernel_launch(void* const* d_in, const int* in_sizes, int n_in,
                              void* d_out, int out_size, void* d_ws,
                              size_t ws_size, hipStream_t stream)
{
  const float* x    = (const float*)d_in[0];
  const float* W_in = (const float*)d_in[1];
  const float* b_in = (const float*)d_in[2];
  const float* Wg   = (const float*)d_in[3];
  const float* bg   = (const float*)d_in[4];
  const float* We   = (const float*)d_in[5];
  const float* be   = (const float*)d_in[6];
  const float* Wo   = (const float*)d_in[7];
  const float* bo   = (const float*)d_in[8];
  const float* Wh   = (const float*)d_in[9];
  const float* bh   = (const float*)d_in[10];
  const float* Wcls = (const float*)d_in[11];
  const float* bcls = (const float*)d_in[12];
  float* out = (float*)d_out;

  char* ws = (char*)d_ws;
  u16* enhb   = (u16*)(ws);                    // 35,651,584  [8192][2176]
  u16* bufF   = (u16*)(ws + 35651584);         // 33,554,432  Wt_in+xb -> expw/h1/h3
  u16* bufA   = (u16*)(ws + 69206016);         //  8,912,896  Wt_e -> Wt_cls
  u16* Wt_o   = (u16*)(ws + 78118912);         //    524,288  [2048][128]
  u16* bufW1  = (u16*)(ws + 78643200);         //  8,388,608  Wh0 -> Wh2
  u16* bufW2  = (u16*)(ws + 87031808);         //  8,388,608  Wh1
  u16* comb   = (u16*)(ws + 95420416);         //  2,097,152  [8192][128]
  float* partials = (float*)(ws + 97517568);   //  1,048,576
  float* gate     = (float*)(ws + 98566144);   //    524,288
  u16* Wt_in  = bufF;                          // [2048][1024], dead after proj
  u16* xb     = bufF + 2097152;                // [8192][1024] bf16, dead after proj
  u16* Wt_e   = bufA;                          // [2048][2176], dead after expert
  u16* Wt_cls = bufA;                          // [1024][2048]

  hipFuncSetAttribute((const void*)gemm8<EP_PROJ>,
                      hipFuncAttributeMaxDynamicSharedMemorySize, 131072);
  hipFuncSetAttribute((const void*)gemm8<EP_EXPERT>,
                      hipFuncAttributeMaxDynamicSharedMemorySize, 131072);
  hipFuncSetAttribute((const void*)gemm8<EP_CTX>,
                      hipFuncAttributeMaxDynamicSharedMemorySize, 131072);
  hipFuncSetAttribute((const void*)gemm8<EP_RELU>,
                      hipFuncAttributeMaxDynamicSharedMemorySize, 131072);
  hipFuncSetAttribute((const void*)gemm8<EP_OUT>,
                      hipFuncAttributeMaxDynamicSharedMemorySize, 131072);

  // ---- conversions needed before the first GEMMs
  f32_to_bf16_k<<<4096, 256, 0, stream>>>(x, xb);
  transpose_conv_k<<<dim3(32, 16, 1), 256, 0, stream>>>(W_in, Wt_in, 1024, 2048, 1024, 0, 0);
  transpose_conv_k<<<dim3(2, 34, 16), 256, 0, stream>>>(We, Wt_e, 2176, 128, 2176, 2176L * 128L, 128);
  transpose_conv_k<<<dim3(32, 2, 1), 256, 0, stream>>>(Wo, Wt_o, 128, 2048, 128, 0, 0);
  // Wh0 -> bufW1, Wh1 -> bufW2 (contiguous): one z=2 launch
  transpose_conv_k<<<dim3(32, 32, 2), 256, 0, stream>>>(Wh, bufW1, 2048, 2048, 2048, 2048L * 2048L, 2048);

  // 1) proj = x @ W_in + b_in -> enhb[:, :2048] + row partial sums
  gemm8<EP_PROJ><<<dim3(8, 32), 512, 131072, stream>>>(
      xb, Wt_in, b_in, (void*)enhb, nullptr, partials, 1024, 1024, 1024, 2176, 2048);
  // 2) phasor bank -> enhb[:, 2048:]
  temporal_k<<<8192, 128, 0, stream>>>(partials, enhb);
  // 3) softmax gate
  gate_k<<<1024, 128, 0, stream>>>(enhb, Wg, bg, gate);
  // 4) experts: relu(enh @ We + be) * gate
  gemm8<EP_EXPERT><<<dim3(8, 32), 512, 131072, stream>>>(
      enhb, Wt_e, be, (void*)bufF, gate, nullptr, 2176, 2176, 2176, 2048, 2048);
  // Wt_e dead -> convert Wcls into bufA
  transpose_conv_k<<<dim3(16, 32, 1), 256, 0, stream>>>(Wcls, Wt_cls, 2048, 1000, 2048, 0, 0);
  // 5) combine experts
  combine_k<<<512, 256, 0, stream>>>(bufF, comb);
  // 6) context = comb @ Wo + bo, cols<20 doubled -> attended (enhb region)
  gemm8<EP_CTX><<<dim3(8, 32), 512, 131072, stream>>>(
      comb, Wt_o, bo, (void*)enhb, nullptr, nullptr, 128, 128, 128, 2048, 2048);
  // 7) MLP: h1 -> bufF, h2 -> enhb, h3 -> bufF
  gemm8<EP_RELU><<<dim3(8, 32), 512, 131072, stream>>>(
      enhb, bufW1, bh, (void*)bufF, nullptr, nullptr, 2048, 2048, 2048, 2048, 2048);
  transpose_conv_k<<<dim3(32, 32, 1), 256, 0, stream>>>(Wh + 2L * 2048L * 2048L, bufW1, 2048, 2048, 2048, 0, 0);
  gemm8<EP_RELU><<<dim3(8, 32), 512, 131072, stream>>>(
      bufF, bufW2, bh + 2048, (void*)enhb, nullptr, nullptr, 2048, 2048, 2048, 2048, 2048);
  gemm8<EP_RELU><<<dim3(8, 32), 512, 131072, stream>>>(
      enhb, bufW1, bh + 4096, (void*)bufF, nullptr, nullptr, 2048, 2048, 2048, 2048, 2048);
  // 8) logits (N=1000 -> padded 1024; Wt_cls rows >=1000 are zero; stores masked)
  gemm8<EP_OUT><<<dim3(4, 32), 512, 131072, stream>>>(
      bufF, Wt_cls, bcls, (void*)out, nullptr, nullptr, 2048, 2048, 2048, 1000, 1000);
}

// Round 6
// 426.201 us; speedup vs baseline: 3.6046x; 1.0019x over previous
//
#include <hip/hip_runtime.h>
#include <math.h>

// ---------------------------------------------------------------------------
// SophisticatedBioInspiredModel — bf16 MFMA, 256^2 8-phase GEMMs (gfx950).
//
// Spiking attention is data-independent: 100 distinct tokens, each bumped once
// from decayed-zero -> v=1.0 < 1.2 -> no spikes -> counts==0 -> top_k(zeros,20)
// = indices 0..19 -> gains double cols 0..19 of context.
//
// GEMM: C = A(MxK,bf16) * Bt(NxK,bf16)^T. 256x256 tile, BK=64, 8 waves (2Mx4N),
// 128 KiB LDS double-buffer. m201-mapped 8-phase schedule: every phase =
// {ds_reads ; 1 half-tile stage ; 16 MFMA ; barrier}, quadrant order
// (aE*b01, aO*b01, aO*b23, aE*b23); stages target the region whose reads
// completed last phase; counted vmcnt(4) at P4/P8 only. Compiler emits counted
// lgkm waits (reads are plain LDS loads). chunk^(row&7) swizzle, setprio,
// bijective XCD swizzle, LDS-restaged coalesced stores.
// ---------------------------------------------------------------------------

typedef unsigned short u16;
typedef __attribute__((ext_vector_type(8))) short bfrag8;
typedef __attribute__((ext_vector_type(4))) float facc4;

__device__ __forceinline__ u16 f2bf(float f) {
  union { float f; unsigned u; } c; c.f = f;
  unsigned u = c.u;
  return (u16)((u + 0x7fffu + ((u >> 16) & 1u)) >> 16);
}
__device__ __forceinline__ float bf2f(u16 h) {
  union { unsigned u; float f; } c; c.u = ((unsigned)h) << 16;
  return c.f;
}
__device__ __forceinline__ void gload16(const void* g, void* lds) {
  __builtin_amdgcn_global_load_lds(
      (const __attribute__((address_space(1))) unsigned*)g,
      (__attribute__((address_space(3))) unsigned*)lds, 16, 0, 0);
}

#define BARX() do { __builtin_amdgcn_sched_barrier(0); \
  __builtin_amdgcn_s_barrier(); __builtin_amdgcn_sched_barrier(0); } while (0)
#define VMW4() do { asm volatile("s_waitcnt vmcnt(4)" ::: "memory"); \
  __builtin_amdgcn_sched_barrier(0); } while (0)

#define RDA_(dst, mbase, dbuf) do { \
  char* _b = smem + (dbuf) * 65536; \
  _Pragma("unroll") for (int mm = 0; mm < 4; ++mm) { \
    int _row = wr * 128 + ((mbase) + mm) * 16 + r15; \
    _Pragma("unroll") for (int ks = 0; ks < 2; ++ks) \
      dst[mm][ks] = *(const bfrag8*)(_b + _row * 128 + \
                                     (((g + ks * 4) ^ (_row & 7)) << 4)); \
  } } while (0)

#define RDB_(dst, nbase, dbuf) do { \
  char* _b = smem + (dbuf) * 65536 + 32768; \
  _Pragma("unroll") for (int nn = 0; nn < 2; ++nn) { \
    int _row = wc * 64 + ((nbase) + nn) * 16 + r15; \
    _Pragma("unroll") for (int ks = 0; ks < 2; ++ks) \
      dst[nn][ks] = *(const bfrag8*)(_b + _row * 128 + \
                                     (((g + ks * 4) ^ (_row & 7)) << 4)); \
  } } while (0)

#define MF_(a, b, mo, no) do { \
  __builtin_amdgcn_s_setprio(1); \
  _Pragma("unroll") for (int mm = 0; mm < 4; ++mm) \
  _Pragma("unroll") for (int nn = 0; nn < 2; ++nn) \
  _Pragma("unroll") for (int ks = 0; ks < 2; ++ks) \
    acc[(mo) + mm][(no) + nn] = __builtin_amdgcn_mfma_f32_16x16x32_bf16( \
        a[mm][ks], b[nn][ks], acc[(mo) + mm][(no) + nn], 0, 0, 0); \
  __builtin_amdgcn_s_setprio(0); \
} while (0)

enum { EP_PROJ = 0, EP_EXPERT = 1, EP_CTX = 2, EP_RELU = 3, EP_OUT = 4 };

// Grid: (N/256, M/256). K%64==0, K/64 even and >=2. A rows %256==0, Bt rows %256==0.
template<int EP>
__global__ __launch_bounds__(512, 2)
void gemm8(const u16* __restrict__ A, const u16* __restrict__ Bt,
           const float* __restrict__ bias, void* __restrict__ Cp,
           const float* __restrict__ gate, float* __restrict__ partials,
           int K, int lda, int ldb, int ldc, int nvalid)
{
  extern __shared__ char smem[];   // 131072 B: [dbuf][A 32K | B 32K]
  const int t = threadIdx.x;
  const int lane = t & 63, wid = t >> 6;
  const int wr = wid >> 2, wc = wid & 3;
  const int g = lane >> 4, r15 = lane & 15;

  // bijective XCD swizzle (nblk % 8 == 0 for all our grids)
  const int nblk = gridDim.x * gridDim.y;
  const int flat = blockIdx.y * gridDim.x + blockIdx.x;
  const int swz = (flat & 7) * (nblk >> 3) + (flat >> 3);
  const int bx = swz % gridDim.x, by = swz / gridDim.x;

  const long a0 = (long)(by * 256) * lda;
  const long b0 = (long)(bx * 256) * ldb;

  facc4 acc[8][4];
#pragma unroll
  for (int m = 0; m < 8; m++)
#pragma unroll
    for (int n = 0; n < 4; n++) acc[m][n] = (facc4){0.f, 0.f, 0.f, 0.f};

  const int r0 = t >> 3, c0s = t & 7;
  const int csw = ((c0s ^ (r0 & 7)) << 3);   // swizzled k-chunk (elems)

  // which: 0=A-half0, 1=A-half1, 2=B-half0, 3=B-half1
  auto STAGE = [&](int kt, int which, int dbuf) {
    const int half = which & 1;
    const u16* gsrc;
    int ld;
    char* ldst = smem + dbuf * 65536 + half * 16384;
    if (which < 2) { gsrc = A + a0; ld = lda; }
    else           { gsrc = Bt + b0; ld = ldb; ldst += 32768; }
    gsrc += (long)(half * 128 + r0) * ld + kt * 64 + csw;
    gload16(gsrc, ldst + (t << 4));
    gload16(gsrc + 64L * ld, ldst + ((512 + t) << 4));
  };

  const int NT = K >> 6;
  STAGE(0, 0, 0); STAGE(0, 1, 0); STAGE(0, 2, 0); STAGE(0, 3, 0);
  STAGE(1, 0, 1); STAGE(1, 1, 1);
  VMW4(); BARX();

  bfrag8 aE[4][2], aO[4][2], b01[2][2], b23[2][2];

  for (int it = 0; it < (NT >> 1); ++it) {
    const int T = 2 * it;
    const int tp1 = T + 1;
    const int tp2 = (T + 2 < NT) ? T + 2 : NT - 1;
    const int tp3 = (T + 3 < NT) ? T + 3 : NT - 1;
    // P1: read aE,b01 (buf0=T); stage (T+1).B0 -> buf1; MFMA aE*b01
    RDA_(aE, 0, 0); RDB_(b01, 0, 0); STAGE(tp1, 2, 1);
    MF_(aE, b01, 0, 0); BARX();
    // P2: read aO; stage (T+1).B1; MFMA aO*b01   (buf0.A reads done here)
    RDA_(aO, 4, 0); STAGE(tp1, 3, 1);
    MF_(aO, b01, 4, 0); BARX();
    // P3: read b23; stage (T+2).A0 -> buf0; MFMA aO*b23 (buf0.B reads done)
    RDB_(b23, 2, 0); STAGE(tp2, 0, 0);
    MF_(aO, b23, 4, 2); BARX();
    // P4: stage (T+2).A1 -> buf0; MFMA aE*b23; drain so buf1(T+1) complete
    STAGE(tp2, 1, 0);
    MF_(aE, b23, 0, 2); VMW4(); BARX();
    // P5-P8: mirror on buf1 (T+1), staging (T+2).B / (T+3).A
    RDA_(aE, 0, 1); RDB_(b01, 0, 1); STAGE(tp2, 2, 0);
    MF_(aE, b01, 0, 0); BARX();
    RDA_(aO, 4, 1); STAGE(tp2, 3, 0);
    MF_(aO, b01, 4, 0); BARX();
    RDB_(b23, 2, 1); STAGE(tp3, 0, 1);
    MF_(aO, b23, 4, 2); BARX();
    STAGE(tp3, 1, 1);
    MF_(aE, b23, 0, 2); VMW4(); BARX();
  }

  // ---- epilogue: drain prefetches (they alias slab space), then LDS restage.
  asm volatile("s_waitcnt vmcnt(0)" ::: "memory");
  __builtin_amdgcn_sched_barrier(0);
  __builtin_amdgcn_s_barrier();
  __builtin_amdgcn_sched_barrier(0);

  const int rbase = by * 256 + wr * 128;
  const int cbase = bx * 256 + wc * 64;
  float* slab = (float*)(smem + wid * 8704);   // per-wave [32][68] f32

  float psum[8][4];
  if (EP == EP_PROJ) {
#pragma unroll
    for (int m = 0; m < 8; m++)
#pragma unroll
      for (int r = 0; r < 4; r++) psum[m][r] = 0.f;
  }

#pragma unroll
  for (int pass = 0; pass < 4; ++pass) {
#pragma unroll
    for (int mm = 0; mm < 2; ++mm) {
      const int m = pass * 2 + mm;
#pragma unroll
      for (int n = 0; n < 4; ++n)
#pragma unroll
        for (int r = 0; r < 4; ++r) {
          const int rowp = mm * 16 + g * 4 + r;
          const int grow = rbase + m * 16 + g * 4 + r;
          const int gcol = cbase + n * 16 + r15;
          float val = acc[m][n][r] + bias[gcol];
          if (EP == EP_EXPERT)
            val = fmaxf(val, 0.f) * gate[(long)grow * 16 + (gcol >> 7)];
          if (EP == EP_CTX && gcol < 20) val *= 2.0f;   // spiking attention
          if (EP == EP_RELU) val = fmaxf(val, 0.f);
          if (EP == EP_PROJ) psum[m][r] += val;
          slab[rowp * 68 + n * 16 + r15] = val;
        }
    }
    // wave-private slab; DS ops in-order within a wave (compiler inserts waits)
#pragma unroll
    for (int rep = 0; rep < 4; ++rep) {
      const int rowp = rep * 8 + (lane >> 3);
      const int cc = (lane & 7) * 8;
      const facc4 v0 = *(const facc4*)&slab[rowp * 68 + cc];
      const facc4 v1 = *(const facc4*)&slab[rowp * 68 + cc + 4];
      const long grow = rbase + pass * 32 + rowp;
      const int gcol0 = cbase + cc;
      if (EP == EP_OUT) {
        float* Cf = (float*)Cp;
        if (gcol0 + 7 < nvalid) {
          *(facc4*)(Cf + grow * ldc + gcol0) = v0;
          *(facc4*)(Cf + grow * ldc + gcol0 + 4) = v1;
        } else {
#pragma unroll
          for (int j = 0; j < 4; ++j)
            if (gcol0 + j < nvalid) Cf[grow * ldc + gcol0 + j] = v0[j];
#pragma unroll
          for (int j = 0; j < 4; ++j)
            if (gcol0 + 4 + j < nvalid) Cf[grow * ldc + gcol0 + 4 + j] = v1[j];
        }
      } else {
        u16 o[8];
        o[0] = f2bf(v0[0]); o[1] = f2bf(v0[1]);
        o[2] = f2bf(v0[2]); o[3] = f2bf(v0[3]);
        o[4] = f2bf(v1[0]); o[5] = f2bf(v1[1]);
        o[6] = f2bf(v1[2]); o[7] = f2bf(v1[3]);
        *(uint4*)((u16*)Cp + grow * ldc + gcol0) = *(const uint4*)o;
      }
    }
  }

  if (EP == EP_PROJ) {
#pragma unroll
    for (int m = 0; m < 8; m++)
#pragma unroll
      for (int r = 0; r < 4; r++) {
        float p = psum[m][r];
        p += __shfl_xor(p, 1); p += __shfl_xor(p, 2);
        p += __shfl_xor(p, 4); p += __shfl_xor(p, 8);
        if (r15 == 0)
          partials[(long)(rbase + m * 16 + g * 4 + r) * 32 + bx * 4 + wc] = p;
      }
  }
}

// out[n][k] = bf16(in[k][n]); pads rows n>=N with zeros. Grid: (ceil(N/64), K/64, Z).
__global__ __launch_bounds__(256)
void transpose_conv_k(const float* __restrict__ in, u16* __restrict__ out,
                      int K, int N, int ldout, long in_zstride, int out_zrows)
{
  __shared__ float tile[64][65];
  const int t = threadIdx.x;
  const int n0 = blockIdx.x * 64, k0 = blockIdx.y * 64;
  const float* src = in + (long)blockIdx.z * in_zstride;
  const int rr = t >> 4;
  const int cc = (t & 15) * 4;
#pragma unroll
  for (int j = 0; j < 4; j++) {
    int k = k0 + j * 16 + rr;
    int n = n0 + cc;
    float v0 = 0.f, v1 = 0.f, v2 = 0.f, v3 = 0.f;
    if (n + 3 < N) {
      facc4 v = *(const facc4*)(src + (long)k * N + n);
      v0 = v[0]; v1 = v[1]; v2 = v[2]; v3 = v[3];
    } else {
      if (n < N)     v0 = src[(long)k * N + n];
      if (n + 1 < N) v1 = src[(long)k * N + n + 1];
      if (n + 2 < N) v2 = src[(long)k * N + n + 2];
      if (n + 3 < N) v3 = src[(long)k * N + n + 3];
    }
    float* trow = &tile[j * 16 + rr][cc];
    trow[0] = v0; trow[1] = v1; trow[2] = v2; trow[3] = v3;
  }
  __syncthreads();
  const int n_l = t >> 2;
  const int kc = (t & 3) * 16;
  const int n_gl = n0 + n_l;
  u16 o16[16];
  const bool valid = n_gl < N;
#pragma unroll
  for (int i = 0; i < 16; i++) o16[i] = valid ? f2bf(tile[kc + i][n_l]) : (u16)0;
  long orow = (long)blockIdx.z * out_zrows + n_gl;
  u16* dst = out + orow * (long)ldout + k0 + kc;
  *(uint4*)dst = ((const uint4*)o16)[0];
  *(uint4*)(dst + 8) = ((const uint4*)o16)[1];
}

__global__ __launch_bounds__(256)
void f32_to_bf16_k(const float* __restrict__ in, u16* __restrict__ out)
{
  const long i = ((long)blockIdx.x * 256 + threadIdx.x) * 8;
  facc4 v0 = *(const facc4*)(in + i);
  facc4 v1 = *(const facc4*)(in + i + 4);
  u16 o[8];
  o[0] = f2bf(v0[0]); o[1] = f2bf(v0[1]); o[2] = f2bf(v0[2]); o[3] = f2bf(v0[3]);
  o[4] = f2bf(v1[0]); o[5] = f2bf(v1[1]); o[6] = f2bf(v1[2]); o[7] = f2bf(v1[3]);
  *(uint4*)(out + i) = *(const uint4*)o;
}

__global__ __launch_bounds__(128)
void temporal_k(const float* __restrict__ partials, u16* __restrict__ enh)
{
  __shared__ float tsh;
  const int b = blockIdx.x;
  const int j = threadIdx.x;  // 128
  if (j < 32) {
    float p = partials[(long)b * 32 + j];
    p += __shfl_xor(p, 1); p += __shfl_xor(p, 2); p += __shfl_xor(p, 4);
    p += __shfl_xor(p, 8); p += __shfl_xor(p, 16);
    if (j == 0) tsh = p;
  }
  __syncthreads();
  float tmean = tsh * (1.0f / 2048.0f);
  float v;
  if (j < 64) v = sinf(7.0f * tmean * (float)(j + 1));
  else        v = cosf(7.0f * tmean * (float)(j - 63));
  enh[(long)b * 2176 + 2048 + j] = f2bf(v);
}

// gate = softmax(enh @ Wg + bg); 8 rows/block staged in LDS once.
__global__ __launch_bounds__(128)
void gate_k(const u16* __restrict__ enh, const float* __restrict__ Wg,
            const float* __restrict__ bg, float* __restrict__ gate)
{
  __shared__ u16 lds[8][2184];   // +8 pad: banks spread
  const int t = threadIdx.x;
  const long row0 = (long)blockIdx.x * 8;
#pragma unroll
  for (int r8 = 0; r8 < 8; ++r8) {
    const u16* src = enh + (row0 + r8) * 2176;
    u16* dst = &lds[r8][0];
    *(uint4*)(dst + t * 8) = *(const uint4*)(src + t * 8);
    *(uint4*)(dst + (128 + t) * 8) = *(const uint4*)(src + (128 + t) * 8);
    if (t < 16)
      *(uint4*)(dst + (256 + t) * 8) = *(const uint4*)(src + (256 + t) * 8);
  }
  __syncthreads();
  const int r = t >> 4, e = t & 15;
  float acc = bg[e];
  for (int k = 0; k < 2176; k += 8) {
    uint4 a = *(const uint4*)&lds[r][k];
    const u16* ap = (const u16*)&a;
#pragma unroll
    for (int j = 0; j < 8; ++j)
      acc += bf2f(ap[j]) * Wg[(k + j) * 16 + e];
  }
  float mx = acc;
  mx = fmaxf(mx, __shfl_xor(mx, 8)); mx = fmaxf(mx, __shfl_xor(mx, 4));
  mx = fmaxf(mx, __shfl_xor(mx, 2)); mx = fmaxf(mx, __shfl_xor(mx, 1));
  float ex = expf(acc - mx);
  float sum = ex;
  sum += __shfl_xor(sum, 8); sum += __shfl_xor(sum, 4);
  sum += __shfl_xor(sum, 2); sum += __shfl_xor(sum, 1);
  gate[(row0 + r) * 16 + e] = ex / sum;
}

// comb[b][k] = sum_e expw[b][e*128+k], 8 k's per thread
__global__ __launch_bounds__(256)
void combine_k(const u16* __restrict__ expw, u16* __restrict__ comb)
{
  const long i = ((long)blockIdx.x * 256 + threadIdx.x) * 8;
  const long b = i >> 7;
  const int k = (int)(i & 127);
  float s[8] = {0.f, 0.f, 0.f, 0.f, 0.f, 0.f, 0.f, 0.f};
#pragma unroll
  for (int e = 0; e < 16; ++e) {
    uint4 v = *(const uint4*)(expw + b * 2048 + e * 128 + k);
    const u16* vp = (const u16*)&v;
#pragma unroll
    for (int j = 0; j < 8; ++j) s[j] += bf2f(vp[j]);
  }
  u16 o[8];
#pragma unroll
  for (int j = 0; j < 8; ++j) o[j] = f2bf(s[j]);
  *(uint4*)(comb + i) = *(const uint4*)o;
}

extern "C" void kernel_launch(void* const* d_in, const int* in_sizes, int n_in,
                              void* d_out, int out_size, void* d_ws,
                              size_t ws_size, hipStream_t stream)
{
  const float* x    = (const float*)d_in[0];
  const float* W_in = (const float*)d_in[1];
  const float* b_in = (const float*)d_in[2];
  const float* Wg   = (const float*)d_in[3];
  const float* bg   = (const float*)d_in[4];
  const float* We   = (const float*)d_in[5];
  const float* be   = (const float*)d_in[6];
  const float* Wo   = (const float*)d_in[7];
  const float* bo   = (const float*)d_in[8];
  const float* Wh   = (const float*)d_in[9];
  const float* bh   = (const float*)d_in[10];
  const float* Wcls = (const float*)d_in[11];
  const float* bcls = (const float*)d_in[12];
  float* out = (float*)d_out;

  char* ws = (char*)d_ws;
  u16* enhb   = (u16*)(ws);                    // 35,651,584  [8192][2176]
  u16* bufF   = (u16*)(ws + 35651584);         // 33,554,432  Wt_in+xb -> expw/h1/h3
  u16* bufA   = (u16*)(ws + 69206016);         //  8,912,896  Wt_e -> Wt_cls
  u16* Wt_o   = (u16*)(ws + 78118912);         //    524,288  [2048][128]
  u16* bufW1  = (u16*)(ws + 78643200);         //  8,388,608  Wh0 -> Wh2
  u16* bufW2  = (u16*)(ws + 87031808);         //  8,388,608  Wh1
  u16* comb   = (u16*)(ws + 95420416);         //  2,097,152  [8192][128]
  float* partials = (float*)(ws + 97517568);   //  1,048,576
  float* gate     = (float*)(ws + 98566144);   //    524,288
  u16* Wt_in  = bufF;                          // [2048][1024], dead after proj
  u16* xb     = bufF + 2097152;                // [8192][1024] bf16, dead after proj
  u16* Wt_e   = bufA;                          // [2048][2176], dead after expert
  u16* Wt_cls = bufA;                          // [1024][2048]

  hipFuncSetAttribute((const void*)gemm8<EP_PROJ>,
                      hipFuncAttributeMaxDynamicSharedMemorySize, 131072);
  hipFuncSetAttribute((const void*)gemm8<EP_EXPERT>,
                      hipFuncAttributeMaxDynamicSharedMemorySize, 131072);
  hipFuncSetAttribute((const void*)gemm8<EP_CTX>,
                      hipFuncAttributeMaxDynamicSharedMemorySize, 131072);
  hipFuncSetAttribute((const void*)gemm8<EP_RELU>,
                      hipFuncAttributeMaxDynamicSharedMemorySize, 131072);
  hipFuncSetAttribute((const void*)gemm8<EP_OUT>,
                      hipFuncAttributeMaxDynamicSharedMemorySize, 131072);

  // ---- conversions needed before the first GEMMs
  f32_to_bf16_k<<<4096, 256, 0, stream>>>(x, xb);
  transpose_conv_k<<<dim3(32, 16, 1), 256, 0, stream>>>(W_in, Wt_in, 1024, 2048, 1024, 0, 0);
  transpose_conv_k<<<dim3(2, 34, 16), 256, 0, stream>>>(We, Wt_e, 2176, 128, 2176, 2176L * 128L, 128);
  transpose_conv_k<<<dim3(32, 2, 1), 256, 0, stream>>>(Wo, Wt_o, 128, 2048, 128, 0, 0);
  // Wh0 -> bufW1, Wh1 -> bufW2 (contiguous): one z=2 launch
  transpose_conv_k<<<dim3(32, 32, 2), 256, 0, stream>>>(Wh, bufW1, 2048, 2048, 2048, 2048L * 2048L, 2048);

  // 1) proj = x @ W_in + b_in -> enhb[:, :2048] + row partial sums
  gemm8<EP_PROJ><<<dim3(8, 32), 512, 131072, stream>>>(
      xb, Wt_in, b_in, (void*)enhb, nullptr, partials, 1024, 1024, 1024, 2176, 2048);
  // 2) phasor bank -> enhb[:, 2048:]
  temporal_k<<<8192, 128, 0, stream>>>(partials, enhb);
  // 3) softmax gate
  gate_k<<<1024, 128, 0, stream>>>(enhb, Wg, bg, gate);
  // 4) experts: relu(enh @ We + be) * gate
  gemm8<EP_EXPERT><<<dim3(8, 32), 512, 131072, stream>>>(
      enhb, Wt_e, be, (void*)bufF, gate, nullptr, 2176, 2176, 2176, 2048, 2048);
  // Wt_e dead -> convert Wcls into bufA
  transpose_conv_k<<<dim3(16, 32, 1), 256, 0, stream>>>(Wcls, Wt_cls, 2048, 1000, 2048, 0, 0);
  // 5) combine experts
  combine_k<<<512, 256, 0, stream>>>(bufF, comb);
  // 6) context = comb @ Wo + bo, cols<20 doubled -> attended (enhb region)
  gemm8<EP_CTX><<<dim3(8, 32), 512, 131072, stream>>>(
      comb, Wt_o, bo, (void*)enhb, nullptr, nullptr, 128, 128, 128, 2048, 2048);
  // 7) MLP: h1 -> bufF, h2 -> enhb, h3 -> bufF
  gemm8<EP_RELU><<<dim3(8, 32), 512, 131072, stream>>>(
      enhb, bufW1, bh, (void*)bufF, nullptr, nullptr, 2048, 2048, 2048, 2048, 2048);
  transpose_conv_k<<<dim3(32, 32, 1), 256, 0, stream>>>(Wh + 2L * 2048L * 2048L, bufW1, 2048, 2048, 2048, 0, 0);
  gemm8<EP_RELU><<<dim3(8, 32), 512, 131072, stream>>>(
      bufF, bufW2, bh + 2048, (void*)enhb, nullptr, nullptr, 2048, 2048, 2048, 2048, 2048);
  gemm8<EP_RELU><<<dim3(8, 32), 512, 131072, stream>>>(
      enhb, bufW1, bh + 4096, (void*)bufF, nullptr, nullptr, 2048, 2048, 2048, 2048, 2048);
  // 8) logits (N=1000 -> padded 1024; Wt_cls rows >=1000 are zero; stores masked)
  gemm8<EP_OUT><<<dim3(4, 32), 512, 131072, stream>>>(
      bufF, Wt_cls, bcls, (void*)out, nullptr, nullptr, 2048, 2048, 2048, 1000, 1000);
}